// Round 1
// baseline (1285.620 us; speedup 1.0000x reference)
//
#include <hip/hip_runtime.h>
#include <math.h>

#define NN 100000
#define NE 1600000
#define DIN 128
#define HC1 128
#define NH 4
#define C1 32
#define C2 64
#define NEG 0.2f

// ---------------- CSR build ----------------

__global__ void k_hist(const int* __restrict__ dstI, const float* __restrict__ ew,
                       int* __restrict__ deg, float* __restrict__ params) {
    int tid = blockIdx.x * blockDim.x + threadIdx.x;
    int stride = gridDim.x * blockDim.x;
    float local = 0.f;
    for (int e = tid; e < NE; e += stride) {
        local += ew[e];
        atomicAdd(&deg[dstI[e]], 1);
    }
    // wave reduce, one atomic per wave
    for (int o = 32; o > 0; o >>= 1) local += __shfl_down(local, o, 64);
    if ((threadIdx.x & 63) == 0) atomicAdd(&params[0], local);
}

__global__ void k_setup(const float* __restrict__ We1, const float* __restrict__ ae1,
                        const float* __restrict__ We2, const float* __restrict__ ae2,
                        float* __restrict__ params) {
    __shared__ float sm[128];
    int t = threadIdx.x;
    sm[t] = We1[t] * ae1[t];
    __syncthreads();
    if (t < 4) {
        float s = 0.f;
        for (int c = 0; c < 32; c++) s += sm[t * 32 + c];
        params[2 + t] = s;            // ce1[h]
    }
    __syncthreads();
    if (t < 64) sm[t] = We2[t] * ae2[t];
    __syncthreads();
    if (t == 0) {
        float s = 0.f;
        for (int c = 0; c < 64; c++) s += sm[c];
        params[6] = s;                // ce2
        params[1] = params[0] / (float)NE;  // mean edge weight
    }
}

__global__ void k_scan(const int* __restrict__ deg, int* __restrict__ rowptr,
                       int* __restrict__ cursor) {
    __shared__ int wsum[16];
    const int T = 1024;
    int t = threadIdx.x;
    int chunk = (NN + T - 1) / T;
    int lo = t * chunk, hi = min(lo + chunk, NN);
    int s = 0;
    for (int i = lo; i < hi; i++) s += deg[i];
    int lane = t & 63, wid = t >> 6;
    int v = s;
    for (int o = 1; o < 64; o <<= 1) { int u = __shfl_up(v, o, 64); if (lane >= o) v += u; }
    if (lane == 63) wsum[wid] = v;
    __syncthreads();
    if (wid == 0) {
        int w = (lane < 16) ? wsum[lane] : 0;
        for (int o = 1; o < 16; o <<= 1) { int u = __shfl_up(w, o, 64); if (lane >= o) w += u; }
        if (lane < 16) wsum[lane] = w;
    }
    __syncthreads();
    int excl = (v - s) + (wid > 0 ? wsum[wid - 1] : 0);
    int run = excl;
    for (int i = lo; i < hi; i++) { rowptr[i] = run; cursor[i] = run; run += deg[i]; }
    if (t == T - 1) rowptr[NN] = run;   // == NE (last thread's range is empty)
}

__global__ void k_scatter(const int* __restrict__ srcI, const int* __restrict__ dstI,
                          const float* __restrict__ ew, int* __restrict__ cursor,
                          int* __restrict__ col, float* __restrict__ ewp) {
    int tid = blockIdx.x * blockDim.x + threadIdx.x;
    int stride = gridDim.x * blockDim.x;
    for (int e = tid; e < NE; e += stride) {
        int d = dstI[e];
        int idx = atomicAdd(&cursor[d], 1);
        col[idx] = srcI[e];
        ewp[idx] = ew[e];
    }
}

// ---------------- Layer 1 GEMM: xs1 = x @ W1, fused alpha_src/alpha_dst ----------------

__global__ void k_gemm1(const float* __restrict__ x, const float* __restrict__ W1,
                        const float* __restrict__ asv, const float* __restrict__ adv,
                        float* __restrict__ xs1, float* __restrict__ as1, float* __restrict__ ad1) {
    extern __shared__ float w1s[];      // 128*128 f32 = 64 KB
    for (int i = threadIdx.x; i < 128 * 128; i += blockDim.x) w1s[i] = W1[i];
    __syncthreads();
    int wid = threadIdx.x >> 6, lane = threadIdx.x & 63;
    int wavesTotal = gridDim.x * 4;
    float a0 = asv[2 * lane], a1 = asv[2 * lane + 1];
    float d0 = adv[2 * lane], d1 = adv[2 * lane + 1];
    for (int r = blockIdx.x * 4 + wid; r < NN; r += wavesTotal) {
        const float4* xr = (const float4*)(x + (size_t)r * 128);
        float acc0 = 0.f, acc1 = 0.f;
        #pragma unroll 8
        for (int d4 = 0; d4 < 32; d4++) {
            float4 xv = xr[d4];
            int base = (d4 * 4) * 128 + 2 * lane;
            float2 w;
            w = *(const float2*)(w1s + base);       acc0 += xv.x * w.x; acc1 += xv.x * w.y;
            w = *(const float2*)(w1s + base + 128); acc0 += xv.y * w.x; acc1 += xv.y * w.y;
            w = *(const float2*)(w1s + base + 256); acc0 += xv.z * w.x; acc1 += xv.z * w.y;
            w = *(const float2*)(w1s + base + 384); acc0 += xv.w * w.x; acc1 += xv.w * w.y;
        }
        *(float2*)(xs1 + (size_t)r * 128 + 2 * lane) = make_float2(acc0, acc1);
        float ps = acc0 * a0 + acc1 * a1;
        float pd = acc0 * d0 + acc1 * d1;
        for (int o = 1; o < 16; o <<= 1) { ps += __shfl_xor(ps, o, 64); pd += __shfl_xor(pd, o, 64); }
        if ((lane & 15) == 0) { int h = lane >> 4; as1[r * 4 + h] = ps; ad1[r * 4 + h] = pd; }
    }
}

// ---------------- Layer 1 aggregation: online segment softmax + weighted sum + ELU ----------------

__global__ void k_agg1(const float* __restrict__ xs1, const float* __restrict__ as1,
                       const float* __restrict__ ad1, const int* __restrict__ rowptr,
                       const int* __restrict__ col, const float* __restrict__ ewp,
                       const float* __restrict__ params, const float* __restrict__ b1,
                       float* __restrict__ h1) {
    int wid = threadIdx.x >> 6, lane = threadIdx.x & 63;
    int n = blockIdx.x * 4 + wid;
    if (n >= NN) return;
    int h = lane >> 4;
    float ce = params[2 + h];
    float meanw = params[1];
    float adn = ad1[n * 4 + h];
    // self loop first
    float m = as1[n * 4 + h] + adn + meanw * ce;
    m = m > 0.f ? m : NEG * m;
    float s = 1.0f;
    float2 acc = *(const float2*)(xs1 + (size_t)n * 128 + 2 * lane);
    int lo = rowptr[n], hi = rowptr[n + 1];
    for (int i = lo; i < hi; i++) {
        int srcN = col[i];
        float w = ewp[i];
        float a = as1[srcN * 4 + h] + adn + w * ce;
        a = a > 0.f ? a : NEG * a;
        float2 xv = *(const float2*)(xs1 + (size_t)srcN * 128 + 2 * lane);
        float newm = fmaxf(m, a);
        float scale = __expf(m - newm);
        float p = __expf(a - newm);
        s = s * scale + p;
        acc.x = acc.x * scale + p * xv.x;
        acc.y = acc.y * scale + p * xv.y;
        m = newm;
    }
    float inv = 1.0f / (s + 1e-16f);
    float o0 = acc.x * inv + b1[2 * lane];
    float o1 = acc.y * inv + b1[2 * lane + 1];
    o0 = o0 > 0.f ? o0 : (__expf(o0) - 1.0f);   // ELU
    o1 = o1 > 0.f ? o1 : (__expf(o1) - 1.0f);
    *(float2*)(h1 + (size_t)n * 128 + 2 * lane) = make_float2(o0, o1);
}

// ---------------- Layer 2 GEMM: xs2 = h1 @ W2, fused alpha_src/alpha_dst ----------------

__global__ void k_gemm2(const float* __restrict__ h1, const float* __restrict__ W2,
                        const float* __restrict__ asv, const float* __restrict__ adv,
                        float* __restrict__ xs2, float* __restrict__ as2, float* __restrict__ ad2) {
    extern __shared__ float w2s[];      // 128*64 f32 = 32 KB
    for (int i = threadIdx.x; i < 128 * 64; i += blockDim.x) w2s[i] = W2[i];
    __syncthreads();
    int wid = threadIdx.x >> 6, lane = threadIdx.x & 63;
    int wavesTotal = gridDim.x * 4;
    float av = asv[lane], dv = adv[lane];
    for (int r = blockIdx.x * 4 + wid; r < NN; r += wavesTotal) {
        const float4* xr = (const float4*)(h1 + (size_t)r * 128);
        float acc = 0.f;
        #pragma unroll 8
        for (int d4 = 0; d4 < 32; d4++) {
            float4 xv = xr[d4];
            acc += xv.x * w2s[(d4 * 4 + 0) * 64 + lane];
            acc += xv.y * w2s[(d4 * 4 + 1) * 64 + lane];
            acc += xv.z * w2s[(d4 * 4 + 2) * 64 + lane];
            acc += xv.w * w2s[(d4 * 4 + 3) * 64 + lane];
        }
        xs2[(size_t)r * 64 + lane] = acc;
        float ps = acc * av, pd = acc * dv;
        for (int o = 1; o < 64; o <<= 1) { ps += __shfl_xor(ps, o, 64); pd += __shfl_xor(pd, o, 64); }
        if (lane == 0) { as2[r] = ps; ad2[r] = pd; }
    }
}

// ---------------- Layer 2 aggregation ----------------

__global__ void k_agg2(const float* __restrict__ xs2, const float* __restrict__ as2,
                       const float* __restrict__ ad2, const int* __restrict__ rowptr,
                       const int* __restrict__ col, const float* __restrict__ ewp,
                       const float* __restrict__ params, const float* __restrict__ b2,
                       float* __restrict__ out) {
    int wid = threadIdx.x >> 6, lane = threadIdx.x & 63;
    int n = blockIdx.x * 4 + wid;
    if (n >= NN) return;
    float ce = params[6];
    float meanw = params[1];
    float adn = ad2[n];
    float m = as2[n] + adn + meanw * ce;
    m = m > 0.f ? m : NEG * m;
    float s = 1.0f;
    float acc = xs2[(size_t)n * 64 + lane];
    int lo = rowptr[n], hi = rowptr[n + 1];
    for (int i = lo; i < hi; i++) {
        int srcN = col[i];
        float w = ewp[i];
        float a = as2[srcN] + adn + w * ce;
        a = a > 0.f ? a : NEG * a;
        float xv = xs2[(size_t)srcN * 64 + lane];
        float newm = fmaxf(m, a);
        float scale = __expf(m - newm);
        float p = __expf(a - newm);
        s = s * scale + p;
        acc = acc * scale + p * xv;
        m = newm;
    }
    out[(size_t)n * 64 + lane] = acc / (s + 1e-16f) + b2[lane];
}

extern "C" void kernel_launch(void* const* d_in, const int* in_sizes, int n_in,
                              void* d_out, int out_size, void* d_ws, size_t ws_size,
                              hipStream_t stream) {
    const float* x    = (const float*)d_in[0];
    const int*   ei   = (const int*)d_in[1];
    const float* ew   = (const float*)d_in[2];
    const float* W1   = (const float*)d_in[3];
    const float* as1v = (const float*)d_in[4];
    const float* ad1v = (const float*)d_in[5];
    const float* ae1v = (const float*)d_in[6];
    const float* We1  = (const float*)d_in[7];
    const float* b1   = (const float*)d_in[8];
    const float* W2   = (const float*)d_in[9];
    const float* as2v = (const float*)d_in[10];
    const float* ad2v = (const float*)d_in[11];
    const float* ae2v = (const float*)d_in[12];
    const float* We2  = (const float*)d_in[13];
    const float* b2   = (const float*)d_in[14];
    const int* srcI = ei;
    const int* dstI = ei + NE;

    float* wsf = (float*)d_ws;
    size_t off = 0;
    auto alloc = [&](size_t nelts) { float* p = wsf + off; off += (nelts + 63) & ~(size_t)63; return p; };
    float* params = alloc(64);
    int*   deg    = (int*)alloc(NN);
    int*   rowptr = (int*)alloc(NN + 1);
    int*   cursor = (int*)alloc(NN);
    int*   col    = (int*)alloc(NE);
    float* ewp    = alloc(NE);
    float* as1    = alloc(NN * 4);
    float* ad1    = alloc(NN * 4);
    float* xs1    = alloc((size_t)NN * 128);
    float* h1     = alloc((size_t)NN * 128);
    // layer-2 scratch reuses layer-1 buffers (xs1/as1/ad1 dead after k_agg1)
    float* xs2 = xs1;
    float* as2 = as1;
    float* ad2 = ad1;

    // zero params + deg (contiguous at ws start)
    hipMemsetAsync(d_ws, 0, (64 + NN + 64) * sizeof(float), stream);

    k_hist   <<<2048, 256, 0, stream>>>(dstI, ew, deg, params);
    k_setup  <<<1, 128, 0, stream>>>(We1, ae1v, We2, ae2v, params);
    k_scan   <<<1, 1024, 0, stream>>>(deg, rowptr, cursor);
    k_scatter<<<2048, 256, 0, stream>>>(srcI, dstI, ew, cursor, col, ewp);
    k_gemm1  <<<512, 256, 65536, stream>>>(x, W1, as1v, ad1v, xs1, as1, ad1);
    k_agg1   <<<25000, 256, 0, stream>>>(xs1, as1, ad1, rowptr, col, ewp, params, b1, h1);
    k_gemm2  <<<512, 256, 32768, stream>>>(h1, W2, as2v, ad2v, xs2, as2, ad2);
    k_agg2   <<<25000, 256, 0, stream>>>(xs2, as2, ad2, rowptr, col, ewp, params, b2, (float*)d_out);
}

// Round 2
// 973.479 us; speedup vs baseline: 1.3206x; 1.3206x over previous
//
#include <hip/hip_runtime.h>
#include <math.h>

#define NN 100000
#define NE 1600000
#define DIN 128
#define NH 4
#define C1 32
#define C2 64
#define NEG 0.2f

// ---------------- CSR build ----------------

__global__ void k_hist(const int* __restrict__ dstI, const float* __restrict__ ew,
                       int* __restrict__ deg, float* __restrict__ params) {
    int tid = blockIdx.x * blockDim.x + threadIdx.x;
    int stride = gridDim.x * blockDim.x;
    float local = 0.f;
    for (int e = tid; e < NE; e += stride) {
        local += ew[e];
        atomicAdd(&deg[dstI[e]], 1);
    }
    for (int o = 32; o > 0; o >>= 1) local += __shfl_down(local, o, 64);
    if ((threadIdx.x & 63) == 0) atomicAdd(&params[0], local);
}

__global__ void k_setup(const float* __restrict__ We1, const float* __restrict__ ae1,
                        const float* __restrict__ We2, const float* __restrict__ ae2,
                        float* __restrict__ params) {
    __shared__ float sm[128];
    int t = threadIdx.x;
    sm[t] = We1[t] * ae1[t];
    __syncthreads();
    if (t < 4) {
        float s = 0.f;
        for (int c = 0; c < 32; c++) s += sm[t * 32 + c];
        params[2 + t] = s;            // ce1[h]
    }
    __syncthreads();
    if (t < 64) sm[t] = We2[t] * ae2[t];
    __syncthreads();
    if (t == 0) {
        float s = 0.f;
        for (int c = 0; c < 64; c++) s += sm[c];
        params[6] = s;                // ce2
        params[1] = params[0] / (float)NE;  // mean edge weight
    }
}

__global__ void k_scan(const int* __restrict__ deg, int* __restrict__ rowptr,
                       int* __restrict__ cursor) {
    __shared__ int wsum[16];
    const int T = 1024;
    int t = threadIdx.x;
    int chunk = (NN + T - 1) / T;
    int lo = t * chunk, hi = min(lo + chunk, NN);
    int s = 0;
    for (int i = lo; i < hi; i++) s += deg[i];
    int lane = t & 63, wid = t >> 6;
    int v = s;
    for (int o = 1; o < 64; o <<= 1) { int u = __shfl_up(v, o, 64); if (lane >= o) v += u; }
    if (lane == 63) wsum[wid] = v;
    __syncthreads();
    if (wid == 0) {
        int w = (lane < 16) ? wsum[lane] : 0;
        for (int o = 1; o < 16; o <<= 1) { int u = __shfl_up(w, o, 64); if (lane >= o) w += u; }
        if (lane < 16) wsum[lane] = w;
    }
    __syncthreads();
    int excl = (v - s) + (wid > 0 ? wsum[wid - 1] : 0);
    int run = excl;
    for (int i = lo; i < hi; i++) { rowptr[i] = run; cursor[i] = run; run += deg[i]; }
    if (t == T - 1) rowptr[NN] = run;
}

__global__ void k_scatter(const int* __restrict__ srcI, const int* __restrict__ dstI,
                          const float* __restrict__ ew, int* __restrict__ cursor,
                          int2* __restrict__ edge2) {
    int tid = blockIdx.x * blockDim.x + threadIdx.x;
    int stride = gridDim.x * blockDim.x;
    for (int e = tid; e < NE; e += stride) {
        int d = dstI[e];
        int idx = atomicAdd(&cursor[d], 1);
        edge2[idx] = make_int2(srcI[e], __float_as_int(ew[e]));
    }
}

// ---------------- Layer 1 GEMM: xs1 = x @ W1 (+ alpha_src/alpha_dst), 4 rows/wave ----------------

__global__ void k_gemm1(const float* __restrict__ x, const float* __restrict__ W1,
                        const float* __restrict__ asv, const float* __restrict__ adv,
                        float* __restrict__ xs1, float* __restrict__ as1, float* __restrict__ ad1) {
    extern __shared__ float w1s[];      // 128*128 f32 = 64 KB
    for (int i = threadIdx.x; i < 128 * 128; i += blockDim.x) w1s[i] = W1[i];
    __syncthreads();
    int wid = threadIdx.x >> 6, lane = threadIdx.x & 63;
    int wavesTotal = gridDim.x * 4;
    float a0 = asv[2 * lane], a1 = asv[2 * lane + 1];
    float d0 = adv[2 * lane], d1 = adv[2 * lane + 1];
    const int NG = NN / 4;  // 25000 groups of 4 rows
    for (int g = blockIdx.x * 4 + wid; g < NG; g += wavesTotal) {
        int r = g * 4;
        const float4* xr = (const float4*)(x + (size_t)r * 128);
        float acc[4][2];
        #pragma unroll
        for (int j = 0; j < 4; j++) { acc[j][0] = 0.f; acc[j][1] = 0.f; }
        #pragma unroll 4
        for (int d4 = 0; d4 < 32; d4++) {
            float4 xv[4];
            #pragma unroll
            for (int j = 0; j < 4; j++) xv[j] = xr[j * 32 + d4];
            const float* wb = w1s + d4 * 4 * 128 + 2 * lane;
            float2 w0 = *(const float2*)(wb);
            float2 w1 = *(const float2*)(wb + 128);
            float2 w2 = *(const float2*)(wb + 256);
            float2 w3 = *(const float2*)(wb + 384);
            #pragma unroll
            for (int j = 0; j < 4; j++) {
                acc[j][0] += xv[j].x * w0.x; acc[j][1] += xv[j].x * w0.y;
                acc[j][0] += xv[j].y * w1.x; acc[j][1] += xv[j].y * w1.y;
                acc[j][0] += xv[j].z * w2.x; acc[j][1] += xv[j].z * w2.y;
                acc[j][0] += xv[j].w * w3.x; acc[j][1] += xv[j].w * w3.y;
            }
        }
        #pragma unroll
        for (int j = 0; j < 4; j++) {
            *(float2*)(xs1 + (size_t)(r + j) * 128 + 2 * lane) = make_float2(acc[j][0], acc[j][1]);
            float ps = acc[j][0] * a0 + acc[j][1] * a1;
            float pd = acc[j][0] * d0 + acc[j][1] * d1;
            #pragma unroll
            for (int o = 1; o < 16; o <<= 1) { ps += __shfl_xor(ps, o, 64); pd += __shfl_xor(pd, o, 64); }
            if ((lane & 15) == 0) { int h = lane >> 4; as1[(r + j) * 4 + h] = ps; ad1[(r + j) * 4 + h] = pd; }
        }
    }
}

// ---------------- Layer 1 aggregation: max-free segment softmax + weighted sum + ELU ----------------

__global__ void k_agg1(const float* __restrict__ xs1, const float* __restrict__ as1,
                       const float* __restrict__ ad1, const int* __restrict__ rowptr,
                       const int2* __restrict__ edge2,
                       const float* __restrict__ params, const float* __restrict__ b1,
                       float* __restrict__ h1) {
    int wid = threadIdx.x >> 6, lane = threadIdx.x & 63;
    int n = blockIdx.x * 4 + wid;
    if (n >= NN) return;
    int h = lane >> 4;
    float ce = params[2 + h];
    float meanw = params[1];
    float adn = ad1[n * 4 + h];
    // self loop
    float aself = as1[n * 4 + h] + adn + meanw * ce;
    aself = aself > 0.f ? aself : NEG * aself;
    float p = __expf(aself);
    float2 xv = *(const float2*)(xs1 + (size_t)n * 128 + 2 * lane);
    float s0 = p, s1 = 0.f;
    float ax0 = p * xv.x, ay0 = p * xv.y, ax1 = 0.f, ay1 = 0.f;
    int lo = rowptr[n], hi = rowptr[n + 1];
    int i = lo;
    for (; i + 2 <= hi; i += 2) {
        int2 e0 = edge2[i], e1 = edge2[i + 1];
        float a0 = as1[e0.x * 4 + h] + adn + __int_as_float(e0.y) * ce;
        float a1 = as1[e1.x * 4 + h] + adn + __int_as_float(e1.y) * ce;
        a0 = a0 > 0.f ? a0 : NEG * a0;
        a1 = a1 > 0.f ? a1 : NEG * a1;
        float q0 = __expf(a0), q1 = __expf(a1);
        float2 v0 = *(const float2*)(xs1 + (size_t)e0.x * 128 + 2 * lane);
        float2 v1 = *(const float2*)(xs1 + (size_t)e1.x * 128 + 2 * lane);
        s0 += q0; s1 += q1;
        ax0 += q0 * v0.x; ay0 += q0 * v0.y;
        ax1 += q1 * v1.x; ay1 += q1 * v1.y;
    }
    if (i < hi) {
        int2 e0 = edge2[i];
        float a0 = as1[e0.x * 4 + h] + adn + __int_as_float(e0.y) * ce;
        a0 = a0 > 0.f ? a0 : NEG * a0;
        float q0 = __expf(a0);
        float2 v0 = *(const float2*)(xs1 + (size_t)e0.x * 128 + 2 * lane);
        s0 += q0; ax0 += q0 * v0.x; ay0 += q0 * v0.y;
    }
    float inv = 1.0f / (s0 + s1 + 1e-16f);
    float o0 = (ax0 + ax1) * inv + b1[2 * lane];
    float o1 = (ay0 + ay1) * inv + b1[2 * lane + 1];
    o0 = o0 > 0.f ? o0 : (__expf(o0) - 1.0f);   // ELU
    o1 = o1 > 0.f ? o1 : (__expf(o1) - 1.0f);
    *(float2*)(h1 + (size_t)n * 128 + 2 * lane) = make_float2(o0, o1);
}

// ---------------- Layer 2 GEMM: xs2 = h1 @ W2 (+ alphas), 4 rows/wave ----------------

__global__ void k_gemm2(const float* __restrict__ h1, const float* __restrict__ W2,
                        const float* __restrict__ asv, const float* __restrict__ adv,
                        float* __restrict__ xs2, float* __restrict__ as2, float* __restrict__ ad2) {
    extern __shared__ float w2s[];      // 128*64 f32 = 32 KB
    for (int i = threadIdx.x; i < 128 * 64; i += blockDim.x) w2s[i] = W2[i];
    __syncthreads();
    int wid = threadIdx.x >> 6, lane = threadIdx.x & 63;
    int wavesTotal = gridDim.x * 4;
    float av = asv[lane], dv = adv[lane];
    const int NG = NN / 4;
    for (int g = blockIdx.x * 4 + wid; g < NG; g += wavesTotal) {
        int r = g * 4;
        const float4* xr = (const float4*)(h1 + (size_t)r * 128);
        float acc[4];
        #pragma unroll
        for (int j = 0; j < 4; j++) acc[j] = 0.f;
        #pragma unroll 4
        for (int d4 = 0; d4 < 32; d4++) {
            float4 xv[4];
            #pragma unroll
            for (int j = 0; j < 4; j++) xv[j] = xr[j * 32 + d4];
            float w0 = w2s[(d4 * 4 + 0) * 64 + lane];
            float w1 = w2s[(d4 * 4 + 1) * 64 + lane];
            float w2v = w2s[(d4 * 4 + 2) * 64 + lane];
            float w3 = w2s[(d4 * 4 + 3) * 64 + lane];
            #pragma unroll
            for (int j = 0; j < 4; j++) {
                acc[j] += xv[j].x * w0;
                acc[j] += xv[j].y * w1;
                acc[j] += xv[j].z * w2v;
                acc[j] += xv[j].w * w3;
            }
        }
        #pragma unroll
        for (int j = 0; j < 4; j++) {
            xs2[(size_t)(r + j) * 64 + lane] = acc[j];
            float ps = acc[j] * av, pd = acc[j] * dv;
            #pragma unroll
            for (int o = 1; o < 64; o <<= 1) { ps += __shfl_xor(ps, o, 64); pd += __shfl_xor(pd, o, 64); }
            if (lane == 0) { as2[r + j] = ps; ad2[r + j] = pd; }
        }
    }
}

// ---------------- Layer 2 aggregation ----------------

__global__ void k_agg2(const float* __restrict__ xs2, const float* __restrict__ as2,
                       const float* __restrict__ ad2, const int* __restrict__ rowptr,
                       const int2* __restrict__ edge2,
                       const float* __restrict__ params, const float* __restrict__ b2,
                       float* __restrict__ out) {
    int wid = threadIdx.x >> 6, lane = threadIdx.x & 63;
    int n = blockIdx.x * 4 + wid;
    if (n >= NN) return;
    float ce = params[6];
    float meanw = params[1];
    float adn = ad2[n];
    float aself = as2[n] + adn + meanw * ce;
    aself = aself > 0.f ? aself : NEG * aself;
    float p = __expf(aself);
    float s0 = p, s1 = 0.f;
    float ac0 = p * xs2[(size_t)n * 64 + lane], ac1 = 0.f;
    int lo = rowptr[n], hi = rowptr[n + 1];
    int i = lo;
    for (; i + 2 <= hi; i += 2) {
        int2 e0 = edge2[i], e1 = edge2[i + 1];
        float a0 = as2[e0.x] + adn + __int_as_float(e0.y) * ce;
        float a1 = as2[e1.x] + adn + __int_as_float(e1.y) * ce;
        a0 = a0 > 0.f ? a0 : NEG * a0;
        a1 = a1 > 0.f ? a1 : NEG * a1;
        float q0 = __expf(a0), q1 = __expf(a1);
        float v0 = xs2[(size_t)e0.x * 64 + lane];
        float v1 = xs2[(size_t)e1.x * 64 + lane];
        s0 += q0; s1 += q1;
        ac0 += q0 * v0; ac1 += q1 * v1;
    }
    if (i < hi) {
        int2 e0 = edge2[i];
        float a0 = as2[e0.x] + adn + __int_as_float(e0.y) * ce;
        a0 = a0 > 0.f ? a0 : NEG * a0;
        float q0 = __expf(a0);
        s0 += q0; ac0 += q0 * xs2[(size_t)e0.x * 64 + lane];
    }
    out[(size_t)n * 64 + lane] = (ac0 + ac1) / (s0 + s1 + 1e-16f) + b2[lane];
}

extern "C" void kernel_launch(void* const* d_in, const int* in_sizes, int n_in,
                              void* d_out, int out_size, void* d_ws, size_t ws_size,
                              hipStream_t stream) {
    const float* x    = (const float*)d_in[0];
    const int*   ei   = (const int*)d_in[1];
    const float* ew   = (const float*)d_in[2];
    const float* W1   = (const float*)d_in[3];
    const float* as1v = (const float*)d_in[4];
    const float* ad1v = (const float*)d_in[5];
    const float* ae1v = (const float*)d_in[6];
    const float* We1  = (const float*)d_in[7];
    const float* b1   = (const float*)d_in[8];
    const float* W2   = (const float*)d_in[9];
    const float* as2v = (const float*)d_in[10];
    const float* ad2v = (const float*)d_in[11];
    const float* ae2v = (const float*)d_in[12];
    const float* We2  = (const float*)d_in[13];
    const float* b2   = (const float*)d_in[14];
    const int* srcI = ei;
    const int* dstI = ei + NE;

    float* wsf = (float*)d_ws;
    size_t off = 0;
    auto alloc = [&](size_t nelts) { float* p = wsf + off; off += (nelts + 63) & ~(size_t)63; return p; };
    float* params = alloc(64);
    int*   deg    = (int*)alloc(NN);
    int*   rowptr = (int*)alloc(NN + 1);
    int*   cursor = (int*)alloc(NN);
    int2*  edge2  = (int2*)alloc((size_t)NE * 2);
    float* as1    = alloc(NN * 4);
    float* ad1    = alloc(NN * 4);
    float* xs1    = alloc((size_t)NN * 128);
    float* h1     = alloc((size_t)NN * 128);
    float* xs2 = xs1;   // layer-2 reuses layer-1 scratch (dead after k_agg1)
    float* as2 = as1;
    float* ad2 = ad1;

    hipMemsetAsync(d_ws, 0, (64 + NN + 64) * sizeof(float), stream);

    k_hist   <<<2048, 256, 0, stream>>>(dstI, ew, deg, params);
    k_setup  <<<1, 128, 0, stream>>>(We1, ae1v, We2, ae2v, params);
    k_scan   <<<1, 1024, 0, stream>>>(deg, rowptr, cursor);
    k_scatter<<<2048, 256, 0, stream>>>(srcI, dstI, ew, cursor, edge2);
    k_gemm1  <<<512, 256, 65536, stream>>>(x, W1, as1v, ad1v, xs1, as1, ad1);
    k_agg1   <<<25000, 256, 0, stream>>>(xs1, as1, ad1, rowptr, edge2, params, b1, h1);
    k_gemm2  <<<512, 256, 32768, stream>>>(h1, W2, as2v, ad2v, xs2, as2, ad2);
    k_agg2   <<<25000, 256, 0, stream>>>(xs2, as2, ad2, rowptr, edge2, params, b2, (float*)d_out);
}

// Round 3
// 775.831 us; speedup vs baseline: 1.6571x; 1.2548x over previous
//
#include <hip/hip_runtime.h>
#include <math.h>

#define NN 100000
#define NE 1600000
#define DIN 128
#define NH 4
#define C1 32
#define C2 64
#define NEG 0.2f

#define SCAN_CHUNK 1024
#define NBLK ((NN + SCAN_CHUNK - 1) / SCAN_CHUNK)   // 98

// ---------------- CSR build ----------------

__global__ void k_hist(const int* __restrict__ dstI, const float* __restrict__ ew,
                       int* __restrict__ deg, float* __restrict__ params) {
    int tid = blockIdx.x * blockDim.x + threadIdx.x;
    int stride = gridDim.x * blockDim.x;
    float local = 0.f;
    for (int e = tid; e < NE; e += stride) {
        local += ew[e];
        atomicAdd(&deg[dstI[e]], 1);
    }
    for (int o = 32; o > 0; o >>= 1) local += __shfl_down(local, o, 64);
    if ((threadIdx.x & 63) == 0) atomicAdd(&params[0], local);
}

__global__ void k_setup(const float* __restrict__ We1, const float* __restrict__ ae1,
                        const float* __restrict__ We2, const float* __restrict__ ae2,
                        float* __restrict__ params) {
    __shared__ float sm[128];
    int t = threadIdx.x;
    sm[t] = We1[t] * ae1[t];
    __syncthreads();
    if (t < 4) {
        float s = 0.f;
        for (int c = 0; c < 32; c++) s += sm[t * 32 + c];
        params[2 + t] = s;            // ce1[h]
    }
    __syncthreads();
    if (t < 64) sm[t] = We2[t] * ae2[t];
    __syncthreads();
    if (t == 0) {
        float s = 0.f;
        for (int c = 0; c < 64; c++) s += sm[c];
        params[6] = s;                // ce2
        params[1] = params[0] / (float)NE;  // mean edge weight
    }
}

// block partial sums
__global__ void k_scanA(const int* __restrict__ deg, int* __restrict__ bsum) {
    __shared__ int ws[4];
    int b = blockIdx.x;
    int base = b * SCAN_CHUNK;
    int t = threadIdx.x;
    int s = 0;
    for (int i = t; i < SCAN_CHUNK; i += 256) {
        int idx = base + i;
        if (idx < NN) s += deg[idx];
    }
    for (int o = 32; o > 0; o >>= 1) s += __shfl_down(s, o, 64);
    int lane = t & 63, wid = t >> 6;
    if (lane == 0) ws[wid] = s;
    __syncthreads();
    if (t == 0) bsum[b] = ws[0] + ws[1] + ws[2] + ws[3];
}

// scan the 98 block sums (1 block, 128 threads = 2 waves)
__global__ void k_scanB(const int* __restrict__ bsum, int* __restrict__ bpre,
                        int* __restrict__ rowptr) {
    __shared__ int wtot[2];
    int t = threadIdx.x;
    int lane = t & 63, wid = t >> 6;
    int v = (t < NBLK) ? bsum[t] : 0;
    int inc = v;
    for (int o = 1; o < 64; o <<= 1) { int u = __shfl_up(inc, o, 64); if (lane >= o) inc += u; }
    if (lane == 63) wtot[wid] = inc;
    __syncthreads();
    if (wid == 1) inc += wtot[0];
    if (t < NBLK) bpre[t] = inc - v;          // exclusive prefix
    if (t == NBLK - 1) rowptr[NN] = inc;      // total == NE
}

// block-local exclusive scan + global offset
__global__ void k_scanC(const int* __restrict__ deg, const int* __restrict__ bpre,
                        int* __restrict__ rowptr, int* __restrict__ cursor) {
    __shared__ int wtot[4];
    int b = blockIdx.x;
    int t = threadIdx.x;
    int lane = t & 63, wid = t >> 6;
    int idx0 = b * SCAN_CHUNK + t * 4;
    int d[4];
    int s = 0;
    #pragma unroll
    for (int j = 0; j < 4; j++) {
        int idx = idx0 + j;
        d[j] = (idx < NN) ? deg[idx] : 0;
        s += d[j];
    }
    int inc = s;
    for (int o = 1; o < 64; o <<= 1) { int u = __shfl_up(inc, o, 64); if (lane >= o) inc += u; }
    if (lane == 63) wtot[wid] = inc;
    __syncthreads();
    int add = bpre[b];
    for (int w = 0; w < wid; w++) add += wtot[w];
    int excl = inc - s + add;
    #pragma unroll
    for (int j = 0; j < 4; j++) {
        int idx = idx0 + j;
        if (idx < NN) { rowptr[idx] = excl; cursor[idx] = excl; }
        excl += d[j];
    }
}

__global__ void k_scatter(const int* __restrict__ srcI, const int* __restrict__ dstI,
                          const float* __restrict__ ew, int* __restrict__ cursor,
                          int2* __restrict__ edge2) {
    int tid = blockIdx.x * blockDim.x + threadIdx.x;
    int stride = gridDim.x * blockDim.x;
    for (int e = tid; e < NE; e += stride) {
        int d = dstI[e];
        int idx = atomicAdd(&cursor[d], 1);
        edge2[idx] = make_int2(srcI[e], __float_as_int(ew[e]));
    }
}

// ---------------- Layer 1 GEMM: xs1 = x @ W1 (+ alpha_src/alpha_dst), 4 rows/wave ----------------

__global__ void k_gemm1(const float* __restrict__ x, const float* __restrict__ W1,
                        const float* __restrict__ asv, const float* __restrict__ adv,
                        float* __restrict__ xs1, float* __restrict__ as1, float* __restrict__ ad1) {
    extern __shared__ float w1s[];      // 128*128 f32 = 64 KB
    for (int i = threadIdx.x; i < 128 * 128; i += blockDim.x) w1s[i] = W1[i];
    __syncthreads();
    int wid = threadIdx.x >> 6, lane = threadIdx.x & 63;
    int wavesTotal = gridDim.x * 4;
    float a0 = asv[2 * lane], a1 = asv[2 * lane + 1];
    float d0 = adv[2 * lane], d1 = adv[2 * lane + 1];
    const int NG = NN / 4;  // 25000 groups of 4 rows
    for (int g = blockIdx.x * 4 + wid; g < NG; g += wavesTotal) {
        int r = g * 4;
        const float4* xr = (const float4*)(x + (size_t)r * 128);
        float acc[4][2];
        #pragma unroll
        for (int j = 0; j < 4; j++) { acc[j][0] = 0.f; acc[j][1] = 0.f; }
        #pragma unroll 4
        for (int d4 = 0; d4 < 32; d4++) {
            float4 xv[4];
            #pragma unroll
            for (int j = 0; j < 4; j++) xv[j] = xr[j * 32 + d4];
            const float* wb = w1s + d4 * 4 * 128 + 2 * lane;
            float2 w0 = *(const float2*)(wb);
            float2 w1 = *(const float2*)(wb + 128);
            float2 w2 = *(const float2*)(wb + 256);
            float2 w3 = *(const float2*)(wb + 384);
            #pragma unroll
            for (int j = 0; j < 4; j++) {
                acc[j][0] += xv[j].x * w0.x; acc[j][1] += xv[j].x * w0.y;
                acc[j][0] += xv[j].y * w1.x; acc[j][1] += xv[j].y * w1.y;
                acc[j][0] += xv[j].z * w2.x; acc[j][1] += xv[j].z * w2.y;
                acc[j][0] += xv[j].w * w3.x; acc[j][1] += xv[j].w * w3.y;
            }
        }
        #pragma unroll
        for (int j = 0; j < 4; j++) {
            *(float2*)(xs1 + (size_t)(r + j) * 128 + 2 * lane) = make_float2(acc[j][0], acc[j][1]);
            float ps = acc[j][0] * a0 + acc[j][1] * a1;
            float pd = acc[j][0] * d0 + acc[j][1] * d1;
            #pragma unroll
            for (int o = 1; o < 16; o <<= 1) { ps += __shfl_xor(ps, o, 64); pd += __shfl_xor(pd, o, 64); }
            if ((lane & 15) == 0) { int h = lane >> 4; as1[(r + j) * 4 + h] = ps; ad1[(r + j) * 4 + h] = pd; }
        }
    }
}

// ---------------- Layer 1 aggregation: max-free segment softmax + weighted sum + ELU ----------------

__global__ void k_agg1(const float* __restrict__ xs1, const float* __restrict__ as1,
                       const float* __restrict__ ad1, const int* __restrict__ rowptr,
                       const int2* __restrict__ edge2,
                       const float* __restrict__ params, const float* __restrict__ b1,
                       float* __restrict__ h1) {
    int wid = threadIdx.x >> 6, lane = threadIdx.x & 63;
    int n = blockIdx.x * 4 + wid;
    if (n >= NN) return;
    int h = lane >> 4;
    float ce = params[2 + h];
    float meanw = params[1];
    float adn = ad1[n * 4 + h];
    float aself = as1[n * 4 + h] + adn + meanw * ce;
    aself = aself > 0.f ? aself : NEG * aself;
    float p = __expf(aself);
    float2 xv = *(const float2*)(xs1 + (size_t)n * 128 + 2 * lane);
    float s0 = p, s1 = 0.f;
    float ax0 = p * xv.x, ay0 = p * xv.y, ax1 = 0.f, ay1 = 0.f;
    int lo = rowptr[n], hi = rowptr[n + 1];
    int i = lo;
    for (; i + 2 <= hi; i += 2) {
        int2 e0 = edge2[i], e1 = edge2[i + 1];
        float a0 = as1[e0.x * 4 + h] + adn + __int_as_float(e0.y) * ce;
        float a1 = as1[e1.x * 4 + h] + adn + __int_as_float(e1.y) * ce;
        a0 = a0 > 0.f ? a0 : NEG * a0;
        a1 = a1 > 0.f ? a1 : NEG * a1;
        float q0 = __expf(a0), q1 = __expf(a1);
        float2 v0 = *(const float2*)(xs1 + (size_t)e0.x * 128 + 2 * lane);
        float2 v1 = *(const float2*)(xs1 + (size_t)e1.x * 128 + 2 * lane);
        s0 += q0; s1 += q1;
        ax0 += q0 * v0.x; ay0 += q0 * v0.y;
        ax1 += q1 * v1.x; ay1 += q1 * v1.y;
    }
    if (i < hi) {
        int2 e0 = edge2[i];
        float a0 = as1[e0.x * 4 + h] + adn + __int_as_float(e0.y) * ce;
        a0 = a0 > 0.f ? a0 : NEG * a0;
        float q0 = __expf(a0);
        float2 v0 = *(const float2*)(xs1 + (size_t)e0.x * 128 + 2 * lane);
        s0 += q0; ax0 += q0 * v0.x; ay0 += q0 * v0.y;
    }
    float inv = 1.0f / (s0 + s1 + 1e-16f);
    float o0 = (ax0 + ax1) * inv + b1[2 * lane];
    float o1 = (ay0 + ay1) * inv + b1[2 * lane + 1];
    o0 = o0 > 0.f ? o0 : (__expf(o0) - 1.0f);   // ELU
    o1 = o1 > 0.f ? o1 : (__expf(o1) - 1.0f);
    *(float2*)(h1 + (size_t)n * 128 + 2 * lane) = make_float2(o0, o1);
}

// ---------------- Layer 2 GEMM: xs2 = h1 @ W2 (+ alphas), 4 rows/wave ----------------

__global__ void k_gemm2(const float* __restrict__ h1, const float* __restrict__ W2,
                        const float* __restrict__ asv, const float* __restrict__ adv,
                        float* __restrict__ xs2, float* __restrict__ as2, float* __restrict__ ad2) {
    extern __shared__ float w2s[];      // 128*64 f32 = 32 KB
    for (int i = threadIdx.x; i < 128 * 64; i += blockDim.x) w2s[i] = W2[i];
    __syncthreads();
    int wid = threadIdx.x >> 6, lane = threadIdx.x & 63;
    int wavesTotal = gridDim.x * 4;
    float av = asv[lane], dv = adv[lane];
    const int NG = NN / 4;
    for (int g = blockIdx.x * 4 + wid; g < NG; g += wavesTotal) {
        int r = g * 4;
        const float4* xr = (const float4*)(h1 + (size_t)r * 128);
        float acc[4];
        #pragma unroll
        for (int j = 0; j < 4; j++) acc[j] = 0.f;
        #pragma unroll 4
        for (int d4 = 0; d4 < 32; d4++) {
            float4 xv[4];
            #pragma unroll
            for (int j = 0; j < 4; j++) xv[j] = xr[j * 32 + d4];
            float w0 = w2s[(d4 * 4 + 0) * 64 + lane];
            float w1 = w2s[(d4 * 4 + 1) * 64 + lane];
            float w2v = w2s[(d4 * 4 + 2) * 64 + lane];
            float w3 = w2s[(d4 * 4 + 3) * 64 + lane];
            #pragma unroll
            for (int j = 0; j < 4; j++) {
                acc[j] += xv[j].x * w0;
                acc[j] += xv[j].y * w1;
                acc[j] += xv[j].z * w2v;
                acc[j] += xv[j].w * w3;
            }
        }
        #pragma unroll
        for (int j = 0; j < 4; j++) {
            xs2[(size_t)(r + j) * 64 + lane] = acc[j];
            float ps = acc[j] * av, pd = acc[j] * dv;
            #pragma unroll
            for (int o = 1; o < 64; o <<= 1) { ps += __shfl_xor(ps, o, 64); pd += __shfl_xor(pd, o, 64); }
            if (lane == 0) { as2[r + j] = ps; ad2[r + j] = pd; }
        }
    }
}

// ---------------- Layer 2 aggregation ----------------

__global__ void k_agg2(const float* __restrict__ xs2, const float* __restrict__ as2,
                       const float* __restrict__ ad2, const int* __restrict__ rowptr,
                       const int2* __restrict__ edge2,
                       const float* __restrict__ params, const float* __restrict__ b2,
                       float* __restrict__ out) {
    int wid = threadIdx.x >> 6, lane = threadIdx.x & 63;
    int n = blockIdx.x * 4 + wid;
    if (n >= NN) return;
    float ce = params[6];
    float meanw = params[1];
    float adn = ad2[n];
    float aself = as2[n] + adn + meanw * ce;
    aself = aself > 0.f ? aself : NEG * aself;
    float p = __expf(aself);
    float s0 = p, s1 = 0.f;
    float ac0 = p * xs2[(size_t)n * 64 + lane], ac1 = 0.f;
    int lo = rowptr[n], hi = rowptr[n + 1];
    int i = lo;
    for (; i + 2 <= hi; i += 2) {
        int2 e0 = edge2[i], e1 = edge2[i + 1];
        float a0 = as2[e0.x] + adn + __int_as_float(e0.y) * ce;
        float a1 = as2[e1.x] + adn + __int_as_float(e1.y) * ce;
        a0 = a0 > 0.f ? a0 : NEG * a0;
        a1 = a1 > 0.f ? a1 : NEG * a1;
        float q0 = __expf(a0), q1 = __expf(a1);
        float v0 = xs2[(size_t)e0.x * 64 + lane];
        float v1 = xs2[(size_t)e1.x * 64 + lane];
        s0 += q0; s1 += q1;
        ac0 += q0 * v0; ac1 += q1 * v1;
    }
    if (i < hi) {
        int2 e0 = edge2[i];
        float a0 = as2[e0.x] + adn + __int_as_float(e0.y) * ce;
        a0 = a0 > 0.f ? a0 : NEG * a0;
        float q0 = __expf(a0);
        s0 += q0; ac0 += q0 * xs2[(size_t)e0.x * 64 + lane];
    }
    out[(size_t)n * 64 + lane] = (ac0 + ac1) / (s0 + s1 + 1e-16f) + b2[lane];
}

extern "C" void kernel_launch(void* const* d_in, const int* in_sizes, int n_in,
                              void* d_out, int out_size, void* d_ws, size_t ws_size,
                              hipStream_t stream) {
    const float* x    = (const float*)d_in[0];
    const int*   ei   = (const int*)d_in[1];
    const float* ew   = (const float*)d_in[2];
    const float* W1   = (const float*)d_in[3];
    const float* as1v = (const float*)d_in[4];
    const float* ad1v = (const float*)d_in[5];
    const float* ae1v = (const float*)d_in[6];
    const float* We1  = (const float*)d_in[7];
    const float* b1   = (const float*)d_in[8];
    const float* W2   = (const float*)d_in[9];
    const float* as2v = (const float*)d_in[10];
    const float* ad2v = (const float*)d_in[11];
    const float* ae2v = (const float*)d_in[12];
    const float* We2  = (const float*)d_in[13];
    const float* b2   = (const float*)d_in[14];
    const int* srcI = ei;
    const int* dstI = ei + NE;

    float* wsf = (float*)d_ws;
    size_t off = 0;
    auto alloc = [&](size_t nelts) { float* p = wsf + off; off += (nelts + 63) & ~(size_t)63; return p; };
    float* params = alloc(64);
    int*   deg    = (int*)alloc(NN);
    int*   rowptr = (int*)alloc(NN + 1);
    int*   cursor = (int*)alloc(NN);
    int*   bsum   = (int*)alloc(NBLK);
    int*   bpre   = (int*)alloc(NBLK);
    int2*  edge2  = (int2*)alloc((size_t)NE * 2);
    float* as1    = alloc(NN * 4);
    float* ad1    = alloc(NN * 4);
    float* xs1    = alloc((size_t)NN * 128);
    float* h1     = alloc((size_t)NN * 128);
    float* xs2 = xs1;   // layer-2 reuses layer-1 scratch (dead after k_agg1)
    float* as2 = as1;
    float* ad2 = ad1;

    hipMemsetAsync(d_ws, 0, (64 + NN + 64) * sizeof(float), stream);

    k_hist   <<<2048, 256, 0, stream>>>(dstI, ew, deg, params);
    k_setup  <<<1, 128, 0, stream>>>(We1, ae1v, We2, ae2v, params);
    k_scanA  <<<NBLK, 256, 0, stream>>>(deg, bsum);
    k_scanB  <<<1, 128, 0, stream>>>(bsum, bpre, rowptr);
    k_scanC  <<<NBLK, 256, 0, stream>>>(deg, bpre, rowptr, cursor);
    k_scatter<<<2048, 256, 0, stream>>>(srcI, dstI, ew, cursor, edge2);
    k_gemm1  <<<512, 256, 65536, stream>>>(x, W1, as1v, ad1v, xs1, as1, ad1);
    k_agg1   <<<25000, 256, 0, stream>>>(xs1, as1, ad1, rowptr, edge2, params, b1, h1);
    k_gemm2  <<<512, 256, 32768, stream>>>(h1, W2, as2v, ad2v, xs2, as2, ad2);
    k_agg2   <<<25000, 256, 0, stream>>>(xs2, as2, ad2, rowptr, edge2, params, b2, (float*)d_out);
}

// Round 4
// 732.623 us; speedup vs baseline: 1.7548x; 1.0590x over previous
//
#include <hip/hip_runtime.h>
#include <math.h>

#define NN 100000
#define NE 1600000
#define DIN 128
#define NH 4
#define C1 32
#define C2 64
#define NEG 0.2f

#define SCAN_CHUNK 1024
#define NBLK ((NN + SCAN_CHUNK - 1) / SCAN_CHUNK)   // 98

// ---------------- CSR build ----------------

__global__ void k_hist(const int* __restrict__ dstI, const float* __restrict__ ew,
                       int* __restrict__ deg, float* __restrict__ params) {
    int tid = blockIdx.x * blockDim.x + threadIdx.x;
    int stride = gridDim.x * blockDim.x;
    float local = 0.f;
    for (int e = tid; e < NE; e += stride) {
        local += ew[e];
        atomicAdd(&deg[dstI[e]], 1);
    }
    for (int o = 32; o > 0; o >>= 1) local += __shfl_down(local, o, 64);
    if ((threadIdx.x & 63) == 0) atomicAdd(&params[0], local);
}

__global__ void k_setup(const float* __restrict__ We1, const float* __restrict__ ae1,
                        const float* __restrict__ We2, const float* __restrict__ ae2,
                        float* __restrict__ params) {
    __shared__ float sm[128];
    int t = threadIdx.x;
    sm[t] = We1[t] * ae1[t];
    __syncthreads();
    if (t < 4) {
        float s = 0.f;
        for (int c = 0; c < 32; c++) s += sm[t * 32 + c];
        params[2 + t] = s;            // ce1[h]
    }
    __syncthreads();
    if (t < 64) sm[t] = We2[t] * ae2[t];
    __syncthreads();
    if (t == 0) {
        float s = 0.f;
        for (int c = 0; c < 64; c++) s += sm[c];
        params[6] = s;                // ce2
        params[1] = params[0] / (float)NE;  // mean edge weight
    }
}

// block partial sums
__global__ void k_scanA(const int* __restrict__ deg, int* __restrict__ bsum) {
    __shared__ int ws[4];
    int b = blockIdx.x;
    int base = b * SCAN_CHUNK;
    int t = threadIdx.x;
    int s = 0;
    for (int i = t; i < SCAN_CHUNK; i += 256) {
        int idx = base + i;
        if (idx < NN) s += deg[idx];
    }
    for (int o = 32; o > 0; o >>= 1) s += __shfl_down(s, o, 64);
    int lane = t & 63, wid = t >> 6;
    if (lane == 0) ws[wid] = s;
    __syncthreads();
    if (t == 0) bsum[b] = ws[0] + ws[1] + ws[2] + ws[3];
}

// scan the 98 block sums (1 block, 128 threads = 2 waves)
__global__ void k_scanB(const int* __restrict__ bsum, int* __restrict__ bpre,
                        int* __restrict__ rowptr) {
    __shared__ int wtot[2];
    int t = threadIdx.x;
    int lane = t & 63, wid = t >> 6;
    int v = (t < NBLK) ? bsum[t] : 0;
    int inc = v;
    for (int o = 1; o < 64; o <<= 1) { int u = __shfl_up(inc, o, 64); if (lane >= o) inc += u; }
    if (lane == 63) wtot[wid] = inc;
    __syncthreads();
    if (wid == 1) inc += wtot[0];
    if (t < NBLK) bpre[t] = inc - v;          // exclusive prefix
    if (t == NBLK - 1) rowptr[NN] = inc;      // total == NE
}

// block-local exclusive scan + global offset
__global__ void k_scanC(const int* __restrict__ deg, const int* __restrict__ bpre,
                        int* __restrict__ rowptr, int* __restrict__ cursor) {
    __shared__ int wtot[4];
    int b = blockIdx.x;
    int t = threadIdx.x;
    int lane = t & 63, wid = t >> 6;
    int idx0 = b * SCAN_CHUNK + t * 4;
    int d[4];
    int s = 0;
    #pragma unroll
    for (int j = 0; j < 4; j++) {
        int idx = idx0 + j;
        d[j] = (idx < NN) ? deg[idx] : 0;
        s += d[j];
    }
    int inc = s;
    for (int o = 1; o < 64; o <<= 1) { int u = __shfl_up(inc, o, 64); if (lane >= o) inc += u; }
    if (lane == 63) wtot[wid] = inc;
    __syncthreads();
    int add = bpre[b];
    for (int w = 0; w < wid; w++) add += wtot[w];
    int excl = inc - s + add;
    #pragma unroll
    for (int j = 0; j < 4; j++) {
        int idx = idx0 + j;
        if (idx < NN) { rowptr[idx] = excl; cursor[idx] = excl; }
        excl += d[j];
    }
}

__global__ void k_scatter(const int* __restrict__ srcI, const int* __restrict__ dstI,
                          const float* __restrict__ ew, int* __restrict__ cursor,
                          int2* __restrict__ edge2) {
    int tid = blockIdx.x * blockDim.x + threadIdx.x;
    int stride = gridDim.x * blockDim.x;
    for (int e = tid; e < NE; e += stride) {
        int d = dstI[e];
        int idx = atomicAdd(&cursor[d], 1);
        edge2[idx] = make_int2(srcI[e], __float_as_int(ew[e]));
    }
}

// ---------------- Layer 1 GEMM: xs1 = x @ W1 (+ alphas), 8 rows/wave, K-split 32KB LDS ----------------

__global__ void __launch_bounds__(256, 5)
k_gemm1(const float* __restrict__ x, const float* __restrict__ W1,
        const float* __restrict__ asv, const float* __restrict__ adv,
        float* __restrict__ xs1, float* __restrict__ as1, float* __restrict__ ad1) {
    __shared__ float w1s[64 * 128];     // 32 KB half-K tile
    int wid = threadIdx.x >> 6, lane = threadIdx.x & 63;
    int r = (blockIdx.x * 4 + wid) * 8;   // 8 rows per wave, grid covers exactly
    float a0 = asv[2 * lane], a1 = asv[2 * lane + 1];
    float d0 = adv[2 * lane], d1 = adv[2 * lane + 1];
    float acc[8][2];
    #pragma unroll
    for (int j = 0; j < 8; j++) { acc[j][0] = 0.f; acc[j][1] = 0.f; }

    for (int t = 0; t < 2; t++) {
        if (t) __syncthreads();            // protect previous tile reads
        const float4* Wg = (const float4*)(W1 + t * 64 * 128);
        float4* Ws = (float4*)w1s;
        for (int i = threadIdx.x; i < 2048; i += 256) Ws[i] = Wg[i];
        __syncthreads();
        #pragma unroll 2
        for (int d4 = 0; d4 < 16; d4++) {
            float4 xv[8];
            #pragma unroll
            for (int j = 0; j < 8; j++)
                xv[j] = ((const float4*)(x + (size_t)(r + j) * 128))[t * 16 + d4];
            const float* wb = w1s + d4 * 4 * 128 + 2 * lane;
            float2 w0 = *(const float2*)(wb);
            float2 w1 = *(const float2*)(wb + 128);
            float2 w2 = *(const float2*)(wb + 256);
            float2 w3 = *(const float2*)(wb + 384);
            #pragma unroll
            for (int j = 0; j < 8; j++) {
                acc[j][0] += xv[j].x * w0.x; acc[j][1] += xv[j].x * w0.y;
                acc[j][0] += xv[j].y * w1.x; acc[j][1] += xv[j].y * w1.y;
                acc[j][0] += xv[j].z * w2.x; acc[j][1] += xv[j].z * w2.y;
                acc[j][0] += xv[j].w * w3.x; acc[j][1] += xv[j].w * w3.y;
            }
        }
    }
    #pragma unroll
    for (int j = 0; j < 8; j++) {
        *(float2*)(xs1 + (size_t)(r + j) * 128 + 2 * lane) = make_float2(acc[j][0], acc[j][1]);
        float ps = acc[j][0] * a0 + acc[j][1] * a1;
        float pd = acc[j][0] * d0 + acc[j][1] * d1;
        #pragma unroll
        for (int o = 1; o < 16; o <<= 1) { ps += __shfl_xor(ps, o, 64); pd += __shfl_xor(pd, o, 64); }
        if ((lane & 15) == 0) { int h = lane >> 4; as1[(r + j) * 4 + h] = ps; ad1[(r + j) * 4 + h] = pd; }
    }
}

// ---------------- Layer 1 aggregation: max-free segment softmax + weighted sum + ELU ----------------

__global__ void k_agg1(const float* __restrict__ xs1, const float* __restrict__ as1,
                       const float* __restrict__ ad1, const int* __restrict__ rowptr,
                       const int2* __restrict__ edge2,
                       const float* __restrict__ params, const float* __restrict__ b1,
                       float* __restrict__ h1) {
    int wid = threadIdx.x >> 6, lane = threadIdx.x & 63;
    int n = blockIdx.x * 4 + wid;
    if (n >= NN) return;
    int h = lane >> 4;
    float ce = params[2 + h];
    float meanw = params[1];
    float adn = ad1[n * 4 + h];
    float aself = as1[n * 4 + h] + adn + meanw * ce;
    aself = aself > 0.f ? aself : NEG * aself;
    float p = __expf(aself);
    float2 xv = *(const float2*)(xs1 + (size_t)n * 128 + 2 * lane);
    float s0 = p, s1 = 0.f;
    float ax0 = p * xv.x, ay0 = p * xv.y, ax1 = 0.f, ay1 = 0.f;
    int lo = rowptr[n], hi = rowptr[n + 1];
    int i = lo;
    for (; i + 2 <= hi; i += 2) {
        int2 e0 = edge2[i], e1 = edge2[i + 1];
        float a0 = as1[e0.x * 4 + h] + adn + __int_as_float(e0.y) * ce;
        float a1 = as1[e1.x * 4 + h] + adn + __int_as_float(e1.y) * ce;
        a0 = a0 > 0.f ? a0 : NEG * a0;
        a1 = a1 > 0.f ? a1 : NEG * a1;
        float q0 = __expf(a0), q1 = __expf(a1);
        float2 v0 = *(const float2*)(xs1 + (size_t)e0.x * 128 + 2 * lane);
        float2 v1 = *(const float2*)(xs1 + (size_t)e1.x * 128 + 2 * lane);
        s0 += q0; s1 += q1;
        ax0 += q0 * v0.x; ay0 += q0 * v0.y;
        ax1 += q1 * v1.x; ay1 += q1 * v1.y;
    }
    if (i < hi) {
        int2 e0 = edge2[i];
        float a0 = as1[e0.x * 4 + h] + adn + __int_as_float(e0.y) * ce;
        a0 = a0 > 0.f ? a0 : NEG * a0;
        float q0 = __expf(a0);
        float2 v0 = *(const float2*)(xs1 + (size_t)e0.x * 128 + 2 * lane);
        s0 += q0; ax0 += q0 * v0.x; ay0 += q0 * v0.y;
    }
    float inv = 1.0f / (s0 + s1 + 1e-16f);
    float o0 = (ax0 + ax1) * inv + b1[2 * lane];
    float o1 = (ay0 + ay1) * inv + b1[2 * lane + 1];
    o0 = o0 > 0.f ? o0 : (__expf(o0) - 1.0f);   // ELU
    o1 = o1 > 0.f ? o1 : (__expf(o1) - 1.0f);
    *(float2*)(h1 + (size_t)n * 128 + 2 * lane) = make_float2(o0, o1);
}

// ---------------- Layer 2 GEMM: xs2 = h1 @ W2 (+ alphas), 8 rows/wave ----------------

__global__ void __launch_bounds__(256, 5)
k_gemm2(const float* __restrict__ h1, const float* __restrict__ W2,
        const float* __restrict__ asv, const float* __restrict__ adv,
        float* __restrict__ xs2, float* __restrict__ as2, float* __restrict__ ad2) {
    __shared__ float w2s[128 * 64];     // 32 KB
    for (int i = threadIdx.x; i < 128 * 64 / 4; i += 256)
        ((float4*)w2s)[i] = ((const float4*)W2)[i];
    __syncthreads();
    int wid = threadIdx.x >> 6, lane = threadIdx.x & 63;
    int r = (blockIdx.x * 4 + wid) * 8;
    float av = asv[lane], dv = adv[lane];
    float acc[8];
    #pragma unroll
    for (int j = 0; j < 8; j++) acc[j] = 0.f;
    #pragma unroll 2
    for (int d4 = 0; d4 < 32; d4++) {
        float4 xv[8];
        #pragma unroll
        for (int j = 0; j < 8; j++)
            xv[j] = ((const float4*)(h1 + (size_t)(r + j) * 128))[d4];
        float w0 = w2s[(d4 * 4 + 0) * 64 + lane];
        float w1 = w2s[(d4 * 4 + 1) * 64 + lane];
        float w2v = w2s[(d4 * 4 + 2) * 64 + lane];
        float w3 = w2s[(d4 * 4 + 3) * 64 + lane];
        #pragma unroll
        for (int j = 0; j < 8; j++) {
            acc[j] += xv[j].x * w0;
            acc[j] += xv[j].y * w1;
            acc[j] += xv[j].z * w2v;
            acc[j] += xv[j].w * w3;
        }
    }
    #pragma unroll
    for (int j = 0; j < 8; j++) {
        xs2[(size_t)(r + j) * 64 + lane] = acc[j];
        float ps = acc[j] * av, pd = acc[j] * dv;
        #pragma unroll
        for (int o = 1; o < 64; o <<= 1) { ps += __shfl_xor(ps, o, 64); pd += __shfl_xor(pd, o, 64); }
        if (lane == 0) { as2[r + j] = ps; ad2[r + j] = pd; }
    }
}

// ---------------- Layer 2 aggregation ----------------

__global__ void k_agg2(const float* __restrict__ xs2, const float* __restrict__ as2,
                       const float* __restrict__ ad2, const int* __restrict__ rowptr,
                       const int2* __restrict__ edge2,
                       const float* __restrict__ params, const float* __restrict__ b2,
                       float* __restrict__ out) {
    int wid = threadIdx.x >> 6, lane = threadIdx.x & 63;
    int n = blockIdx.x * 4 + wid;
    if (n >= NN) return;
    float ce = params[6];
    float meanw = params[1];
    float adn = ad2[n];
    float aself = as2[n] + adn + meanw * ce;
    aself = aself > 0.f ? aself : NEG * aself;
    float p = __expf(aself);
    float s0 = p, s1 = 0.f;
    float ac0 = p * xs2[(size_t)n * 64 + lane], ac1 = 0.f;
    int lo = rowptr[n], hi = rowptr[n + 1];
    int i = lo;
    for (; i + 2 <= hi; i += 2) {
        int2 e0 = edge2[i], e1 = edge2[i + 1];
        float a0 = as2[e0.x] + adn + __int_as_float(e0.y) * ce;
        float a1 = as2[e1.x] + adn + __int_as_float(e1.y) * ce;
        a0 = a0 > 0.f ? a0 : NEG * a0;
        a1 = a1 > 0.f ? a1 : NEG * a1;
        float q0 = __expf(a0), q1 = __expf(a1);
        float v0 = xs2[(size_t)e0.x * 64 + lane];
        float v1 = xs2[(size_t)e1.x * 64 + lane];
        s0 += q0; s1 += q1;
        ac0 += q0 * v0; ac1 += q1 * v1;
    }
    if (i < hi) {
        int2 e0 = edge2[i];
        float a0 = as2[e0.x] + adn + __int_as_float(e0.y) * ce;
        a0 = a0 > 0.f ? a0 : NEG * a0;
        float q0 = __expf(a0);
        s0 += q0; ac0 += q0 * xs2[(size_t)e0.x * 64 + lane];
    }
    out[(size_t)n * 64 + lane] = (ac0 + ac1) / (s0 + s1 + 1e-16f) + b2[lane];
}

extern "C" void kernel_launch(void* const* d_in, const int* in_sizes, int n_in,
                              void* d_out, int out_size, void* d_ws, size_t ws_size,
                              hipStream_t stream) {
    const float* x    = (const float*)d_in[0];
    const int*   ei   = (const int*)d_in[1];
    const float* ew   = (const float*)d_in[2];
    const float* W1   = (const float*)d_in[3];
    const float* as1v = (const float*)d_in[4];
    const float* ad1v = (const float*)d_in[5];
    const float* ae1v = (const float*)d_in[6];
    const float* We1  = (const float*)d_in[7];
    const float* b1   = (const float*)d_in[8];
    const float* W2   = (const float*)d_in[9];
    const float* as2v = (const float*)d_in[10];
    const float* ad2v = (const float*)d_in[11];
    const float* ae2v = (const float*)d_in[12];
    const float* We2  = (const float*)d_in[13];
    const float* b2   = (const float*)d_in[14];
    const int* srcI = ei;
    const int* dstI = ei + NE;

    float* wsf = (float*)d_ws;
    size_t off = 0;
    auto alloc = [&](size_t nelts) { float* p = wsf + off; off += (nelts + 63) & ~(size_t)63; return p; };
    float* params = alloc(64);
    int*   deg    = (int*)alloc(NN);
    int*   rowptr = (int*)alloc(NN + 1);
    int*   cursor = (int*)alloc(NN);
    int*   bsum   = (int*)alloc(NBLK);
    int*   bpre   = (int*)alloc(NBLK);
    int2*  edge2  = (int2*)alloc((size_t)NE * 2);
    float* as1    = alloc(NN * 4);
    float* ad1    = alloc(NN * 4);
    float* xs1    = alloc((size_t)NN * 128);
    float* h1     = alloc((size_t)NN * 128);
    float* xs2 = xs1;   // layer-2 reuses layer-1 scratch (dead after k_agg1)
    float* as2 = as1;
    float* ad2 = ad1;

    hipMemsetAsync(d_ws, 0, (64 + NN + 64) * sizeof(float), stream);

    k_hist   <<<2048, 256, 0, stream>>>(dstI, ew, deg, params);
    k_setup  <<<1, 128, 0, stream>>>(We1, ae1v, We2, ae2v, params);
    k_scanA  <<<NBLK, 256, 0, stream>>>(deg, bsum);
    k_scanB  <<<1, 128, 0, stream>>>(bsum, bpre, rowptr);
    k_scanC  <<<NBLK, 256, 0, stream>>>(deg, bpre, rowptr, cursor);
    k_scatter<<<2048, 256, 0, stream>>>(srcI, dstI, ew, cursor, edge2);
    k_gemm1  <<<3125, 256, 0, stream>>>(x, W1, as1v, ad1v, xs1, as1, ad1);
    k_agg1   <<<25000, 256, 0, stream>>>(xs1, as1, ad1, rowptr, edge2, params, b1, h1);
    k_gemm2  <<<3125, 256, 0, stream>>>(h1, W2, as2v, ad2v, xs2, as2, ad2);
    k_agg2   <<<25000, 256, 0, stream>>>(xs2, as2, ad2, rowptr, edge2, params, b2, (float*)d_out);
}

// Round 5
// 633.560 us; speedup vs baseline: 2.0292x; 1.1564x over previous
//
#include <hip/hip_runtime.h>
#include <math.h>

#define NN 100000
#define NE 1600000
#define DIN 128
#define NH 4
#define C1 32
#define C2 64
#define NEG 0.2f

#define SCAN_CHUNK 1024
#define NBLK ((NN + SCAN_CHUNK - 1) / SCAN_CHUNK)   // 98

// ---------------- CSR build ----------------

__global__ void k_hist(const int* __restrict__ dstI, const float* __restrict__ ew,
                       int* __restrict__ deg, float* __restrict__ params) {
    int tid = blockIdx.x * blockDim.x + threadIdx.x;
    int stride = gridDim.x * blockDim.x;
    float local = 0.f;
    for (int e = tid; e < NE; e += stride) {
        local += ew[e];
        atomicAdd(&deg[dstI[e]], 1);
    }
    for (int o = 32; o > 0; o >>= 1) local += __shfl_down(local, o, 64);
    if ((threadIdx.x & 63) == 0) atomicAdd(&params[0], local);
}

__global__ void k_setup(const float* __restrict__ We1, const float* __restrict__ ae1,
                        const float* __restrict__ We2, const float* __restrict__ ae2,
                        float* __restrict__ params) {
    __shared__ float sm[128];
    int t = threadIdx.x;
    sm[t] = We1[t] * ae1[t];
    __syncthreads();
    if (t < 4) {
        float s = 0.f;
        for (int c = 0; c < 32; c++) s += sm[t * 32 + c];
        params[2 + t] = s;            // ce1[h]
    }
    __syncthreads();
    if (t < 64) sm[t] = We2[t] * ae2[t];
    __syncthreads();
    if (t == 0) {
        float s = 0.f;
        for (int c = 0; c < 64; c++) s += sm[c];
        params[6] = s;                // ce2
        params[1] = params[0] / (float)NE;  // mean edge weight
    }
}

// block partial sums
__global__ void k_scanA(const int* __restrict__ deg, int* __restrict__ bsum) {
    __shared__ int ws[4];
    int b = blockIdx.x;
    int base = b * SCAN_CHUNK;
    int t = threadIdx.x;
    int s = 0;
    for (int i = t; i < SCAN_CHUNK; i += 256) {
        int idx = base + i;
        if (idx < NN) s += deg[idx];
    }
    for (int o = 32; o > 0; o >>= 1) s += __shfl_down(s, o, 64);
    int lane = t & 63, wid = t >> 6;
    if (lane == 0) ws[wid] = s;
    __syncthreads();
    if (t == 0) bsum[b] = ws[0] + ws[1] + ws[2] + ws[3];
}

// scan the 98 block sums (1 block, 128 threads = 2 waves)
__global__ void k_scanB(const int* __restrict__ bsum, int* __restrict__ bpre,
                        int* __restrict__ rowptr) {
    __shared__ int wtot[2];
    int t = threadIdx.x;
    int lane = t & 63, wid = t >> 6;
    int v = (t < NBLK) ? bsum[t] : 0;
    int inc = v;
    for (int o = 1; o < 64; o <<= 1) { int u = __shfl_up(inc, o, 64); if (lane >= o) inc += u; }
    if (lane == 63) wtot[wid] = inc;
    __syncthreads();
    if (wid == 1) inc += wtot[0];
    if (t < NBLK) bpre[t] = inc - v;          // exclusive prefix
    if (t == NBLK - 1) rowptr[NN] = inc;      // total == NE
}

// block-local exclusive scan + global offset
__global__ void k_scanC(const int* __restrict__ deg, const int* __restrict__ bpre,
                        int* __restrict__ rowptr, int* __restrict__ cursor) {
    __shared__ int wtot[4];
    int b = blockIdx.x;
    int t = threadIdx.x;
    int lane = t & 63, wid = t >> 6;
    int idx0 = b * SCAN_CHUNK + t * 4;
    int d[4];
    int s = 0;
    #pragma unroll
    for (int j = 0; j < 4; j++) {
        int idx = idx0 + j;
        d[j] = (idx < NN) ? deg[idx] : 0;
        s += d[j];
    }
    int inc = s;
    for (int o = 1; o < 64; o <<= 1) { int u = __shfl_up(inc, o, 64); if (lane >= o) inc += u; }
    if (lane == 63) wtot[wid] = inc;
    __syncthreads();
    int add = bpre[b];
    for (int w = 0; w < wid; w++) add += wtot[w];
    int excl = inc - s + add;
    #pragma unroll
    for (int j = 0; j < 4; j++) {
        int idx = idx0 + j;
        if (idx < NN) { rowptr[idx] = excl; cursor[idx] = excl; }
        excl += d[j];
    }
}

__global__ void k_scatter(const int* __restrict__ srcI, const int* __restrict__ dstI,
                          const float* __restrict__ ew, int* __restrict__ cursor,
                          int2* __restrict__ edge2) {
    int tid = blockIdx.x * blockDim.x + threadIdx.x;
    int stride = gridDim.x * blockDim.x;
    for (int e = tid; e < NE; e += stride) {
        int d = dstI[e];
        int idx = atomicAdd(&cursor[d], 1);
        edge2[idx] = make_int2(srcI[e], __float_as_int(ew[e]));
    }
}

// ---------------- Layer 1 GEMM: lane=row, wave=head(32 cols), x staged in LDS ----------------

__global__ void __launch_bounds__(256, 4)
k_gemm1(const float* __restrict__ x, const float* __restrict__ W1,
        const float* __restrict__ asv, const float* __restrict__ adv,
        float* __restrict__ xs1, float* __restrict__ as1, float* __restrict__ ad1) {
    __shared__ float xt[64 * 129];     // 64 rows, stride 129 (+1 pad -> 2-way bank = free)
    int t = threadIdx.x;
    int r0 = blockIdx.x * 64;
    // coalesced stage: 64 contiguous rows = 32 KB contiguous
    for (int i = t; i < 2048; i += 256) {
        int row = i >> 5;           // 32 float4 per row
        int c4 = i & 31;
        float4 v = (r0 + row < NN) ? ((const float4*)x)[(size_t)(r0 + row) * 32 + c4]
                                   : make_float4(0.f, 0.f, 0.f, 0.f);
        float* dst = &xt[row * 129 + c4 * 4];
        dst[0] = v.x; dst[1] = v.y; dst[2] = v.z; dst[3] = v.w;
    }
    __syncthreads();
    int wid = t >> 6, lane = t & 63;
    int row = r0 + lane;
    int c0 = __builtin_amdgcn_readfirstlane(wid * 32);   // head = wid; uniform -> s_load W
    float acc[32];
    #pragma unroll
    for (int c = 0; c < 32; c++) acc[c] = 0.f;
    const float* xr = &xt[lane * 129];
    const float* wp = W1 + c0;
    #pragma unroll 2
    for (int k = 0; k < 128; k++) {
        float xv = xr[k];
        const float* wk = wp + k * 128;
        #pragma unroll
        for (int c = 0; c < 32; c++) acc[c] += xv * wk[c];
    }
    if (row < NN) {
        float* orow = xs1 + (size_t)row * 128 + c0;
        #pragma unroll
        for (int j = 0; j < 8; j++)
            *(float4*)(orow + 4 * j) = make_float4(acc[4*j], acc[4*j+1], acc[4*j+2], acc[4*j+3]);
        float ps = 0.f, pd = 0.f;
        #pragma unroll
        for (int c = 0; c < 32; c++) { ps += acc[c] * asv[c0 + c]; pd += acc[c] * adv[c0 + c]; }
        as1[row * 4 + wid] = ps;
        ad1[row * 4 + wid] = pd;
    }
}

// ---------------- Layer 1 aggregation: max-free segment softmax + weighted sum + ELU ----------------

__global__ void k_agg1(const float* __restrict__ xs1, const float* __restrict__ as1,
                       const float* __restrict__ ad1, const int* __restrict__ rowptr,
                       const int2* __restrict__ edge2,
                       const float* __restrict__ params, const float* __restrict__ b1,
                       float* __restrict__ h1) {
    int wid = threadIdx.x >> 6, lane = threadIdx.x & 63;
    int n = blockIdx.x * 4 + wid;
    if (n >= NN) return;
    int h = lane >> 4;
    float ce = params[2 + h];
    float meanw = params[1];
    float adn = ad1[n * 4 + h];
    float aself = as1[n * 4 + h] + adn + meanw * ce;
    aself = aself > 0.f ? aself : NEG * aself;
    float p = __expf(aself);
    float2 xv = *(const float2*)(xs1 + (size_t)n * 128 + 2 * lane);
    float s0 = p, s1 = 0.f;
    float ax0 = p * xv.x, ay0 = p * xv.y, ax1 = 0.f, ay1 = 0.f;
    int lo = rowptr[n], hi = rowptr[n + 1];
    int i = lo;
    for (; i + 2 <= hi; i += 2) {
        int2 e0 = edge2[i], e1 = edge2[i + 1];
        float a0 = as1[e0.x * 4 + h] + adn + __int_as_float(e0.y) * ce;
        float a1 = as1[e1.x * 4 + h] + adn + __int_as_float(e1.y) * ce;
        a0 = a0 > 0.f ? a0 : NEG * a0;
        a1 = a1 > 0.f ? a1 : NEG * a1;
        float q0 = __expf(a0), q1 = __expf(a1);
        float2 v0 = *(const float2*)(xs1 + (size_t)e0.x * 128 + 2 * lane);
        float2 v1 = *(const float2*)(xs1 + (size_t)e1.x * 128 + 2 * lane);
        s0 += q0; s1 += q1;
        ax0 += q0 * v0.x; ay0 += q0 * v0.y;
        ax1 += q1 * v1.x; ay1 += q1 * v1.y;
    }
    if (i < hi) {
        int2 e0 = edge2[i];
        float a0 = as1[e0.x * 4 + h] + adn + __int_as_float(e0.y) * ce;
        a0 = a0 > 0.f ? a0 : NEG * a0;
        float q0 = __expf(a0);
        float2 v0 = *(const float2*)(xs1 + (size_t)e0.x * 128 + 2 * lane);
        s0 += q0; ax0 += q0 * v0.x; ay0 += q0 * v0.y;
    }
    float inv = 1.0f / (s0 + s1 + 1e-16f);
    float o0 = (ax0 + ax1) * inv + b1[2 * lane];
    float o1 = (ay0 + ay1) * inv + b1[2 * lane + 1];
    o0 = o0 > 0.f ? o0 : (__expf(o0) - 1.0f);   // ELU
    o1 = o1 > 0.f ? o1 : (__expf(o1) - 1.0f);
    *(float2*)(h1 + (size_t)n * 128 + 2 * lane) = make_float2(o0, o1);
}

// ---------------- Layer 2 GEMM: lane=row, wave=16-col chunk, h1 staged in LDS ----------------

__global__ void __launch_bounds__(256, 4)
k_gemm2(const float* __restrict__ h1, const float* __restrict__ W2,
        const float* __restrict__ asv, const float* __restrict__ adv,
        float* __restrict__ xs2, float* __restrict__ as2, float* __restrict__ ad2) {
    __shared__ float xt[64 * 129];       // 33 KB
    __shared__ float pp[2][4][64];       // cross-wave alpha partials (2 KB)
    int t = threadIdx.x;
    int r0 = blockIdx.x * 64;
    for (int i = t; i < 2048; i += 256) {
        int row = i >> 5;
        int c4 = i & 31;
        float4 v = (r0 + row < NN) ? ((const float4*)h1)[(size_t)(r0 + row) * 32 + c4]
                                   : make_float4(0.f, 0.f, 0.f, 0.f);
        float* dst = &xt[row * 129 + c4 * 4];
        dst[0] = v.x; dst[1] = v.y; dst[2] = v.z; dst[3] = v.w;
    }
    __syncthreads();
    int wid = t >> 6, lane = t & 63;
    int row = r0 + lane;
    int c0 = __builtin_amdgcn_readfirstlane(wid * 16);
    float acc[16];
    #pragma unroll
    for (int c = 0; c < 16; c++) acc[c] = 0.f;
    const float* xr = &xt[lane * 129];
    const float* wp = W2 + c0;
    #pragma unroll 2
    for (int k = 0; k < 128; k++) {
        float xv = xr[k];
        const float* wk = wp + k * 64;
        #pragma unroll
        for (int c = 0; c < 16; c++) acc[c] += xv * wk[c];
    }
    float ps = 0.f, pd = 0.f;
    #pragma unroll
    for (int c = 0; c < 16; c++) { ps += acc[c] * asv[c0 + c]; pd += acc[c] * adv[c0 + c]; }
    pp[0][wid][lane] = ps;
    pp[1][wid][lane] = pd;
    if (row < NN) {
        float* orow = xs2 + (size_t)row * 64 + c0;
        #pragma unroll
        for (int j = 0; j < 4; j++)
            *(float4*)(orow + 4 * j) = make_float4(acc[4*j], acc[4*j+1], acc[4*j+2], acc[4*j+3]);
    }
    __syncthreads();
    if (wid == 0 && row < NN) {
        as2[row] = pp[0][0][lane] + pp[0][1][lane] + pp[0][2][lane] + pp[0][3][lane];
        ad2[row] = pp[1][0][lane] + pp[1][1][lane] + pp[1][2][lane] + pp[1][3][lane];
    }
}

// ---------------- Layer 2 aggregation ----------------

__global__ void k_agg2(const float* __restrict__ xs2, const float* __restrict__ as2,
                       const float* __restrict__ ad2, const int* __restrict__ rowptr,
                       const int2* __restrict__ edge2,
                       const float* __restrict__ params, const float* __restrict__ b2,
                       float* __restrict__ out) {
    int wid = threadIdx.x >> 6, lane = threadIdx.x & 63;
    int n = blockIdx.x * 4 + wid;
    if (n >= NN) return;
    float ce = params[6];
    float meanw = params[1];
    float adn = ad2[n];
    float aself = as2[n] + adn + meanw * ce;
    aself = aself > 0.f ? aself : NEG * aself;
    float p = __expf(aself);
    float s0 = p, s1 = 0.f;
    float ac0 = p * xs2[(size_t)n * 64 + lane], ac1 = 0.f;
    int lo = rowptr[n], hi = rowptr[n + 1];
    int i = lo;
    for (; i + 2 <= hi; i += 2) {
        int2 e0 = edge2[i], e1 = edge2[i + 1];
        float a0 = as2[e0.x] + adn + __int_as_float(e0.y) * ce;
        float a1 = as2[e1.x] + adn + __int_as_float(e1.y) * ce;
        a0 = a0 > 0.f ? a0 : NEG * a0;
        a1 = a1 > 0.f ? a1 : NEG * a1;
        float q0 = __expf(a0), q1 = __expf(a1);
        float v0 = xs2[(size_t)e0.x * 64 + lane];
        float v1 = xs2[(size_t)e1.x * 64 + lane];
        s0 += q0; s1 += q1;
        ac0 += q0 * v0; ac1 += q1 * v1;
    }
    if (i < hi) {
        int2 e0 = edge2[i];
        float a0 = as2[e0.x] + adn + __int_as_float(e0.y) * ce;
        a0 = a0 > 0.f ? a0 : NEG * a0;
        float q0 = __expf(a0);
        s0 += q0; ac0 += q0 * xs2[(size_t)e0.x * 64 + lane];
    }
    out[(size_t)n * 64 + lane] = (ac0 + ac1) / (s0 + s1 + 1e-16f) + b2[lane];
}

extern "C" void kernel_launch(void* const* d_in, const int* in_sizes, int n_in,
                              void* d_out, int out_size, void* d_ws, size_t ws_size,
                              hipStream_t stream) {
    const float* x    = (const float*)d_in[0];
    const int*   ei   = (const int*)d_in[1];
    const float* ew   = (const float*)d_in[2];
    const float* W1   = (const float*)d_in[3];
    const float* as1v = (const float*)d_in[4];
    const float* ad1v = (const float*)d_in[5];
    const float* ae1v = (const float*)d_in[6];
    const float* We1  = (const float*)d_in[7];
    const float* b1   = (const float*)d_in[8];
    const float* W2   = (const float*)d_in[9];
    const float* as2v = (const float*)d_in[10];
    const float* ad2v = (const float*)d_in[11];
    const float* ae2v = (const float*)d_in[12];
    const float* We2  = (const float*)d_in[13];
    const float* b2   = (const float*)d_in[14];
    const int* srcI = ei;
    const int* dstI = ei + NE;

    float* wsf = (float*)d_ws;
    size_t off = 0;
    auto alloc = [&](size_t nelts) { float* p = wsf + off; off += (nelts + 63) & ~(size_t)63; return p; };
    float* params = alloc(64);
    int*   deg    = (int*)alloc(NN);
    int*   rowptr = (int*)alloc(NN + 1);
    int*   cursor = (int*)alloc(NN);
    int*   bsum   = (int*)alloc(NBLK);
    int*   bpre   = (int*)alloc(NBLK);
    int2*  edge2  = (int2*)alloc((size_t)NE * 2);
    float* as1    = alloc(NN * 4);
    float* ad1    = alloc(NN * 4);
    float* xs1    = alloc((size_t)NN * 128);
    float* h1     = alloc((size_t)NN * 128);
    float* xs2 = xs1;   // layer-2 reuses layer-1 scratch (dead after k_agg1)
    float* as2 = as1;
    float* ad2 = ad1;

    hipMemsetAsync(d_ws, 0, (64 + NN + 64) * sizeof(float), stream);

    k_hist   <<<2048, 256, 0, stream>>>(dstI, ew, deg, params);
    k_setup  <<<1, 128, 0, stream>>>(We1, ae1v, We2, ae2v, params);
    k_scanA  <<<NBLK, 256, 0, stream>>>(deg, bsum);
    k_scanB  <<<1, 128, 0, stream>>>(bsum, bpre, rowptr);
    k_scanC  <<<NBLK, 256, 0, stream>>>(deg, bpre, rowptr, cursor);
    k_scatter<<<2048, 256, 0, stream>>>(srcI, dstI, ew, cursor, edge2);
    k_gemm1  <<<(NN + 63) / 64, 256, 0, stream>>>(x, W1, as1v, ad1v, xs1, as1, ad1);
    k_agg1   <<<25000, 256, 0, stream>>>(xs1, as1, ad1, rowptr, edge2, params, b1, h1);
    k_gemm2  <<<(NN + 63) / 64, 256, 0, stream>>>(h1, W2, as2v, ad2v, xs2, as2, ad2);
    k_agg2   <<<25000, 256, 0, stream>>>(xs2, as2, ad2, rowptr, edge2, params, b2, (float*)d_out);
}

// Round 6
// 573.873 us; speedup vs baseline: 2.2403x; 1.1040x over previous
//
#include <hip/hip_runtime.h>
#include <math.h>

#define NN 100000
#define NE 1600000
#define DIN 128
#define NH 4
#define C1 32
#define C2 64
#define NEG 0.2f

#define SCAN_CHUNK 1024
#define NBLK ((NN + SCAN_CHUNK - 1) / SCAN_CHUNK)   // 98

__device__ __forceinline__ unsigned bf16rtn(float f) {
    unsigned b = __float_as_uint(f);
    return (b + 0x7FFFu + ((b >> 16) & 1u)) >> 16;
}
__device__ __forceinline__ unsigned pack2bf(float lo, float hi) {
    return bf16rtn(lo) | (bf16rtn(hi) << 16);
}

// ---------------- CSR build ----------------

__global__ void k_hist(const int* __restrict__ dstI, int* __restrict__ deg) {
    int tid = blockIdx.x * blockDim.x + threadIdx.x;
    int stride = gridDim.x * blockDim.x;
    for (int e = tid; e < NE; e += stride) atomicAdd(&deg[dstI[e]], 1);
}

__global__ void k_setup(const float* __restrict__ We1, const float* __restrict__ ae1,
                        const float* __restrict__ We2, const float* __restrict__ ae2,
                        float* __restrict__ params) {
    __shared__ float sm[128];
    int t = threadIdx.x;
    sm[t] = We1[t] * ae1[t];
    __syncthreads();
    if (t < 4) {
        float s = 0.f;
        for (int c = 0; c < 32; c++) s += sm[t * 32 + c];
        params[2 + t] = s;            // ce1[h]
    }
    __syncthreads();
    if (t < 64) sm[t] = We2[t] * ae2[t];
    __syncthreads();
    if (t == 0) {
        float s = 0.f;
        for (int c = 0; c < 64; c++) s += sm[c];
        params[6] = s;                // ce2
        params[1] = params[0] / (float)NE;  // mean edge weight
    }
}

// block partial sums
__global__ void k_scanA(const int* __restrict__ deg, int* __restrict__ bsum) {
    __shared__ int ws[4];
    int b = blockIdx.x;
    int base = b * SCAN_CHUNK;
    int t = threadIdx.x;
    int s = 0;
    for (int i = t; i < SCAN_CHUNK; i += 256) {
        int idx = base + i;
        if (idx < NN) s += deg[idx];
    }
    for (int o = 32; o > 0; o >>= 1) s += __shfl_down(s, o, 64);
    int lane = t & 63, wid = t >> 6;
    if (lane == 0) ws[wid] = s;
    __syncthreads();
    if (t == 0) bsum[b] = ws[0] + ws[1] + ws[2] + ws[3];
}

// scan the 98 block sums (1 block, 128 threads = 2 waves)
__global__ void k_scanB(const int* __restrict__ bsum, int* __restrict__ bpre,
                        int* __restrict__ rowptr) {
    __shared__ int wtot[2];
    int t = threadIdx.x;
    int lane = t & 63, wid = t >> 6;
    int v = (t < NBLK) ? bsum[t] : 0;
    int inc = v;
    for (int o = 1; o < 64; o <<= 1) { int u = __shfl_up(inc, o, 64); if (lane >= o) inc += u; }
    if (lane == 63) wtot[wid] = inc;
    __syncthreads();
    if (wid == 1) inc += wtot[0];
    if (t < NBLK) bpre[t] = inc - v;          // exclusive prefix
    if (t == NBLK - 1) rowptr[NN] = inc;      // total == NE
}

// block-local exclusive scan + global offset
__global__ void k_scanC(const int* __restrict__ deg, const int* __restrict__ bpre,
                        int* __restrict__ rowptr, int* __restrict__ cursor) {
    __shared__ int wtot[4];
    int b = blockIdx.x;
    int t = threadIdx.x;
    int lane = t & 63, wid = t >> 6;
    int idx0 = b * SCAN_CHUNK + t * 4;
    int d[4];
    int s = 0;
    #pragma unroll
    for (int j = 0; j < 4; j++) {
        int idx = idx0 + j;
        d[j] = (idx < NN) ? deg[idx] : 0;
        s += d[j];
    }
    int inc = s;
    for (int o = 1; o < 64; o <<= 1) { int u = __shfl_up(inc, o, 64); if (lane >= o) inc += u; }
    if (lane == 63) wtot[wid] = inc;
    __syncthreads();
    int add = bpre[b];
    for (int w = 0; w < wid; w++) add += wtot[w];
    int excl = inc - s + add;
    #pragma unroll
    for (int j = 0; j < 4; j++) {
        int idx = idx0 + j;
        if (idx < NN) { rowptr[idx] = excl; cursor[idx] = excl; }
        excl += d[j];
    }
}

__global__ void k_scatter(const int* __restrict__ srcI, const int* __restrict__ dstI,
                          const float* __restrict__ ew, int* __restrict__ cursor,
                          int2* __restrict__ edge2, float* __restrict__ params) {
    int tid = blockIdx.x * blockDim.x + threadIdx.x;
    int stride = gridDim.x * blockDim.x;
    float local = 0.f;
    for (int e = tid; e < NE; e += stride) {
        int d = dstI[e];
        float w = ew[e];
        local += w;
        int idx = atomicAdd(&cursor[d], 1);
        edge2[idx] = make_int2(srcI[e], __float_as_int(w));
    }
    for (int o = 32; o > 0; o >>= 1) local += __shfl_down(local, o, 64);
    if ((threadIdx.x & 63) == 0) atomicAdd(&params[0], local);
}

// ---------------- Layer 1 GEMM: lane=row, wave=head(32 cols), x staged in LDS; xs1 out bf16 ----------------

__global__ void __launch_bounds__(256, 4)
k_gemm1(const float* __restrict__ x, const float* __restrict__ W1,
        const float* __restrict__ asv, const float* __restrict__ adv,
        unsigned* __restrict__ xs1b, float* __restrict__ as1, float* __restrict__ ad1) {
    __shared__ float xt[64 * 129];     // 64 rows, stride 129 (+1 pad -> 2-way bank = free)
    int t = threadIdx.x;
    int r0 = blockIdx.x * 64;
    for (int i = t; i < 2048; i += 256) {
        int row = i >> 5;           // 32 float4 per row
        int c4 = i & 31;
        float4 v = (r0 + row < NN) ? ((const float4*)x)[(size_t)(r0 + row) * 32 + c4]
                                   : make_float4(0.f, 0.f, 0.f, 0.f);
        float* dst = &xt[row * 129 + c4 * 4];
        dst[0] = v.x; dst[1] = v.y; dst[2] = v.z; dst[3] = v.w;
    }
    __syncthreads();
    int wid = t >> 6, lane = t & 63;
    int row = r0 + lane;
    int c0 = __builtin_amdgcn_readfirstlane(wid * 32);   // head = wid; uniform -> scalar W path
    float acc[32];
    #pragma unroll
    for (int c = 0; c < 32; c++) acc[c] = 0.f;
    const float* xr = &xt[lane * 129];
    const float* wp = W1 + c0;
    #pragma unroll 2
    for (int k = 0; k < 128; k++) {
        float xv = xr[k];
        const float* wk = wp + k * 128;
        #pragma unroll
        for (int c = 0; c < 32; c++) acc[c] += xv * wk[c];
    }
    if (row < NN) {
        // bf16-pack the 32 channels -> 16 uints -> 4x uint4
        unsigned* orow = xs1b + (size_t)row * 64 + wid * 16;
        #pragma unroll
        for (int j = 0; j < 4; j++) {
            uint4 pk;
            pk.x = pack2bf(acc[8*j+0], acc[8*j+1]);
            pk.y = pack2bf(acc[8*j+2], acc[8*j+3]);
            pk.z = pack2bf(acc[8*j+4], acc[8*j+5]);
            pk.w = pack2bf(acc[8*j+6], acc[8*j+7]);
            *(uint4*)(orow + 4*j) = pk;
        }
        float ps = 0.f, pd = 0.f;
        #pragma unroll
        for (int c = 0; c < 32; c++) { ps += acc[c] * asv[c0 + c]; pd += acc[c] * adv[c0 + c]; }
        as1[row * 4 + wid] = ps;
        ad1[row * 4 + wid] = pd;
    }
}

// ---------------- Layer 1 aggregation: bf16 gathers, fp32 softmax/accum, ELU ----------------

__global__ void k_agg1(const unsigned* __restrict__ xs1b, const float* __restrict__ as1,
                       const float* __restrict__ ad1, const int* __restrict__ rowptr,
                       const int2* __restrict__ edge2,
                       const float* __restrict__ params, const float* __restrict__ b1,
                       float* __restrict__ h1) {
    int wid = threadIdx.x >> 6, lane = threadIdx.x & 63;
    int n = blockIdx.x * 4 + wid;
    if (n >= NN) return;
    int h = lane >> 4;
    float ce = params[2 + h];
    float meanw = params[1];
    float adn = ad1[n * 4 + h];
    float aself = as1[n * 4 + h] + adn + meanw * ce;
    aself = aself > 0.f ? aself : NEG * aself;
    float p = __expf(aself);
    unsigned us = xs1b[(size_t)n * 64 + lane];
    float sx = __uint_as_float(us << 16);
    float sy = __uint_as_float(us & 0xFFFF0000u);
    float s0 = p, s1 = 0.f;
    float ax0 = p * sx, ay0 = p * sy, ax1 = 0.f, ay1 = 0.f;
    int lo = rowptr[n], hi = rowptr[n + 1];
    int i = lo;
    for (; i + 2 <= hi; i += 2) {
        int2 e0 = edge2[i], e1 = edge2[i + 1];
        float a0 = as1[e0.x * 4 + h] + adn + __int_as_float(e0.y) * ce;
        float a1 = as1[e1.x * 4 + h] + adn + __int_as_float(e1.y) * ce;
        a0 = a0 > 0.f ? a0 : NEG * a0;
        a1 = a1 > 0.f ? a1 : NEG * a1;
        float q0 = __expf(a0), q1 = __expf(a1);
        unsigned u0 = xs1b[(size_t)e0.x * 64 + lane];
        unsigned u1 = xs1b[(size_t)e1.x * 64 + lane];
        float v0x = __uint_as_float(u0 << 16), v0y = __uint_as_float(u0 & 0xFFFF0000u);
        float v1x = __uint_as_float(u1 << 16), v1y = __uint_as_float(u1 & 0xFFFF0000u);
        s0 += q0; s1 += q1;
        ax0 += q0 * v0x; ay0 += q0 * v0y;
        ax1 += q1 * v1x; ay1 += q1 * v1y;
    }
    if (i < hi) {
        int2 e0 = edge2[i];
        float a0 = as1[e0.x * 4 + h] + adn + __int_as_float(e0.y) * ce;
        a0 = a0 > 0.f ? a0 : NEG * a0;
        float q0 = __expf(a0);
        unsigned u0 = xs1b[(size_t)e0.x * 64 + lane];
        s0 += q0;
        ax0 += q0 * __uint_as_float(u0 << 16);
        ay0 += q0 * __uint_as_float(u0 & 0xFFFF0000u);
    }
    float inv = 1.0f / (s0 + s1 + 1e-16f);
    float o0 = (ax0 + ax1) * inv + b1[2 * lane];
    float o1 = (ay0 + ay1) * inv + b1[2 * lane + 1];
    o0 = o0 > 0.f ? o0 : (__expf(o0) - 1.0f);   // ELU
    o1 = o1 > 0.f ? o1 : (__expf(o1) - 1.0f);
    *(float2*)(h1 + (size_t)n * 128 + 2 * lane) = make_float2(o0, o1);
}

// ---------------- Layer 2 GEMM: lane=row, wave=16-col chunk, h1 staged in LDS; xs2 out bf16 ----------------

__global__ void __launch_bounds__(256, 4)
k_gemm2(const float* __restrict__ h1, const float* __restrict__ W2,
        const float* __restrict__ asv, const float* __restrict__ adv,
        unsigned* __restrict__ xs2b, float* __restrict__ as2, float* __restrict__ ad2) {
    __shared__ float xt[64 * 129];       // 33 KB
    __shared__ float pp[2][4][64];       // cross-wave alpha partials (2 KB)
    int t = threadIdx.x;
    int r0 = blockIdx.x * 64;
    for (int i = t; i < 2048; i += 256) {
        int row = i >> 5;
        int c4 = i & 31;
        float4 v = (r0 + row < NN) ? ((const float4*)h1)[(size_t)(r0 + row) * 32 + c4]
                                   : make_float4(0.f, 0.f, 0.f, 0.f);
        float* dst = &xt[row * 129 + c4 * 4];
        dst[0] = v.x; dst[1] = v.y; dst[2] = v.z; dst[3] = v.w;
    }
    __syncthreads();
    int wid = t >> 6, lane = t & 63;
    int row = r0 + lane;
    int c0 = __builtin_amdgcn_readfirstlane(wid * 16);
    float acc[16];
    #pragma unroll
    for (int c = 0; c < 16; c++) acc[c] = 0.f;
    const float* xr = &xt[lane * 129];
    const float* wp = W2 + c0;
    #pragma unroll 2
    for (int k = 0; k < 128; k++) {
        float xv = xr[k];
        const float* wk = wp + k * 64;
        #pragma unroll
        for (int c = 0; c < 16; c++) acc[c] += xv * wk[c];
    }
    float ps = 0.f, pd = 0.f;
    #pragma unroll
    for (int c = 0; c < 16; c++) { ps += acc[c] * asv[c0 + c]; pd += acc[c] * adv[c0 + c]; }
    pp[0][wid][lane] = ps;
    pp[1][wid][lane] = pd;
    if (row < NN) {
        unsigned* orow = xs2b + (size_t)row * 32 + wid * 8;
        #pragma unroll
        for (int j = 0; j < 2; j++) {
            uint4 pk;
            pk.x = pack2bf(acc[8*j+0], acc[8*j+1]);
            pk.y = pack2bf(acc[8*j+2], acc[8*j+3]);
            pk.z = pack2bf(acc[8*j+4], acc[8*j+5]);
            pk.w = pack2bf(acc[8*j+6], acc[8*j+7]);
            *(uint4*)(orow + 4*j) = pk;
        }
    }
    __syncthreads();
    if (wid == 0 && row < NN) {
        as2[row] = pp[0][0][lane] + pp[0][1][lane] + pp[0][2][lane] + pp[0][3][lane];
        ad2[row] = pp[1][0][lane] + pp[1][1][lane] + pp[1][2][lane] + pp[1][3][lane];
    }
}

// ---------------- Layer 2 aggregation: bf16 gathers (ushort/lane) ----------------

__global__ void k_agg2(const unsigned short* __restrict__ xs2h, const float* __restrict__ as2,
                       const float* __restrict__ ad2, const int* __restrict__ rowptr,
                       const int2* __restrict__ edge2,
                       const float* __restrict__ params, const float* __restrict__ b2,
                       float* __restrict__ out) {
    int wid = threadIdx.x >> 6, lane = threadIdx.x & 63;
    int n = blockIdx.x * 4 + wid;
    if (n >= NN) return;
    float ce = params[6];
    float meanw = params[1];
    float adn = ad2[n];
    float aself = as2[n] + adn + meanw * ce;
    aself = aself > 0.f ? aself : NEG * aself;
    float p = __expf(aself);
    float sv = __uint_as_float(((unsigned)xs2h[(size_t)n * 64 + lane]) << 16);
    float s0 = p, s1 = 0.f;
    float ac0 = p * sv, ac1 = 0.f;
    int lo = rowptr[n], hi = rowptr[n + 1];
    int i = lo;
    for (; i + 2 <= hi; i += 2) {
        int2 e0 = edge2[i], e1 = edge2[i + 1];
        float a0 = as2[e0.x] + adn + __int_as_float(e0.y) * ce;
        float a1 = as2[e1.x] + adn + __int_as_float(e1.y) * ce;
        a0 = a0 > 0.f ? a0 : NEG * a0;
        a1 = a1 > 0.f ? a1 : NEG * a1;
        float q0 = __expf(a0), q1 = __expf(a1);
        float v0 = __uint_as_float(((unsigned)xs2h[(size_t)e0.x * 64 + lane]) << 16);
        float v1 = __uint_as_float(((unsigned)xs2h[(size_t)e1.x * 64 + lane]) << 16);
        s0 += q0; s1 += q1;
        ac0 += q0 * v0; ac1 += q1 * v1;
    }
    if (i < hi) {
        int2 e0 = edge2[i];
        float a0 = as2[e0.x] + adn + __int_as_float(e0.y) * ce;
        a0 = a0 > 0.f ? a0 : NEG * a0;
        float q0 = __expf(a0);
        s0 += q0;
        ac0 += q0 * __uint_as_float(((unsigned)xs2h[(size_t)e0.x * 64 + lane]) << 16);
    }
    out[(size_t)n * 64 + lane] = (ac0 + ac1) / (s0 + s1 + 1e-16f) + b2[lane];
}

extern "C" void kernel_launch(void* const* d_in, const int* in_sizes, int n_in,
                              void* d_out, int out_size, void* d_ws, size_t ws_size,
                              hipStream_t stream) {
    const float* x    = (const float*)d_in[0];
    const int*   ei   = (const int*)d_in[1];
    const float* ew   = (const float*)d_in[2];
    const float* W1   = (const float*)d_in[3];
    const float* as1v = (const float*)d_in[4];
    const float* ad1v = (const float*)d_in[5];
    const float* ae1v = (const float*)d_in[6];
    const float* We1  = (const float*)d_in[7];
    const float* b1   = (const float*)d_in[8];
    const float* W2   = (const float*)d_in[9];
    const float* as2v = (const float*)d_in[10];
    const float* ad2v = (const float*)d_in[11];
    const float* ae2v = (const float*)d_in[12];
    const float* We2  = (const float*)d_in[13];
    const float* b2   = (const float*)d_in[14];
    const int* srcI = ei;
    const int* dstI = ei + NE;

    float* wsf = (float*)d_ws;
    size_t off = 0;
    auto alloc = [&](size_t nelts) { float* p = wsf + off; off += (nelts + 63) & ~(size_t)63; return p; };
    float*    params = alloc(64);
    int*      deg    = (int*)alloc(NN);
    int*      rowptr = (int*)alloc(NN + 1);
    int*      cursor = (int*)alloc(NN);
    int*      bsum   = (int*)alloc(NBLK);
    int*      bpre   = (int*)alloc(NBLK);
    int2*     edge2  = (int2*)alloc((size_t)NE * 2);
    float*    as1    = alloc(NN * 4);
    float*    ad1    = alloc(NN * 4);
    unsigned* xs1b   = (unsigned*)alloc((size_t)NN * 64);   // bf16 [N][128]
    float*    h1     = alloc((size_t)NN * 128);
    unsigned* xs2b   = xs1b;   // layer-2 reuses (xs1b dead after k_agg1)
    float*    as2 = as1;
    float*    ad2 = ad1;

    hipMemsetAsync(d_ws, 0, (64 + NN + 64) * sizeof(float), stream);

    k_hist   <<<2048, 256, 0, stream>>>(dstI, deg);
    k_scanA  <<<NBLK, 256, 0, stream>>>(deg, bsum);
    k_scanB  <<<1, 128, 0, stream>>>(bsum, bpre, rowptr);
    k_scanC  <<<NBLK, 256, 0, stream>>>(deg, bpre, rowptr, cursor);
    k_scatter<<<2048, 256, 0, stream>>>(srcI, dstI, ew, cursor, edge2, params);
    k_setup  <<<1, 128, 0, stream>>>(We1, ae1v, We2, ae2v, params);
    k_gemm1  <<<(NN + 63) / 64, 256, 0, stream>>>(x, W1, as1v, ad1v, xs1b, as1, ad1);
    k_agg1   <<<25000, 256, 0, stream>>>(xs1b, as1, ad1, rowptr, edge2, params, b1, h1);
    k_gemm2  <<<(NN + 63) / 64, 256, 0, stream>>>(h1, W2, as2v, ad2v, xs2b, as2, ad2);
    k_agg2   <<<25000, 256, 0, stream>>>((const unsigned short*)xs2b, as2, ad2, rowptr, edge2, params, b2, (float*)d_out);
}

// Round 7
// 515.346 us; speedup vs baseline: 2.4947x; 1.1136x over previous
//
#include <hip/hip_runtime.h>
#include <math.h>

#define NN 100000
#define NE 1600000
#define DIN 128
#define NH 4
#define C1 32
#define C2 64
#define NEG 0.2f

#define SCAN_CHUNK 1024
#define NBLK ((NN + SCAN_CHUNK - 1) / SCAN_CHUNK)   // 98

#define NBUCK 8
#define BUCKN (NN / NBUCK)          // 12500 nodes per bucket
#define BIN_CHUNK 4096
#define NBINBLK ((NE + BIN_CHUNK - 1) / BIN_CHUNK)  // 391

__device__ __forceinline__ unsigned bf16rtn(float f) {
    unsigned b = __float_as_uint(f);
    return (b + 0x7FFFu + ((b >> 16) & 1u)) >> 16;
}
__device__ __forceinline__ unsigned pack2bf(float lo, float hi) {
    return bf16rtn(lo) | (bf16rtn(hi) << 16);
}

// ---------------- CSR build ----------------

__global__ void k_hist(const int* __restrict__ dstI, int* __restrict__ deg) {
    int tid = blockIdx.x * blockDim.x + threadIdx.x;
    int stride = gridDim.x * blockDim.x;
    for (int e = tid; e < NE; e += stride) atomicAdd(&deg[dstI[e]], 1);
}

__global__ void k_setup(const float* __restrict__ We1, const float* __restrict__ ae1,
                        const float* __restrict__ We2, const float* __restrict__ ae2,
                        float* __restrict__ params) {
    __shared__ float sm[128];
    int t = threadIdx.x;
    sm[t] = We1[t] * ae1[t];
    __syncthreads();
    if (t < 4) {
        float s = 0.f;
        for (int c = 0; c < 32; c++) s += sm[t * 32 + c];
        params[2 + t] = s;            // ce1[h]
    }
    __syncthreads();
    if (t < 64) sm[t] = We2[t] * ae2[t];
    __syncthreads();
    if (t == 0) {
        float s = 0.f;
        for (int c = 0; c < 64; c++) s += sm[c];
        params[6] = s;                // ce2
        params[1] = params[0] / (float)NE;  // mean edge weight
    }
}

// block partial sums
__global__ void k_scanA(const int* __restrict__ deg, int* __restrict__ bsum) {
    __shared__ int ws[4];
    int b = blockIdx.x;
    int base = b * SCAN_CHUNK;
    int t = threadIdx.x;
    int s = 0;
    for (int i = t; i < SCAN_CHUNK; i += 256) {
        int idx = base + i;
        if (idx < NN) s += deg[idx];
    }
    for (int o = 32; o > 0; o >>= 1) s += __shfl_down(s, o, 64);
    int lane = t & 63, wid = t >> 6;
    if (lane == 0) ws[wid] = s;
    __syncthreads();
    if (t == 0) bsum[b] = ws[0] + ws[1] + ws[2] + ws[3];
}

// scan the 98 block sums (1 block, 128 threads = 2 waves)
__global__ void k_scanB(const int* __restrict__ bsum, int* __restrict__ bpre,
                        int* __restrict__ rowptr) {
    __shared__ int wtot[2];
    int t = threadIdx.x;
    int lane = t & 63, wid = t >> 6;
    int v = (t < NBLK) ? bsum[t] : 0;
    int inc = v;
    for (int o = 1; o < 64; o <<= 1) { int u = __shfl_up(inc, o, 64); if (lane >= o) inc += u; }
    if (lane == 63) wtot[wid] = inc;
    __syncthreads();
    if (wid == 1) inc += wtot[0];
    if (t < NBLK) bpre[t] = inc - v;          // exclusive prefix
    if (t == NBLK - 1) rowptr[NN] = inc;      // total == NE
}

// block-local exclusive scan + global offset; also emits bucket bases
__global__ void k_scanC(const int* __restrict__ deg, const int* __restrict__ bpre,
                        int* __restrict__ rowptr, int* __restrict__ cursor,
                        int* __restrict__ bcur) {
    __shared__ int wtot[4];
    int b = blockIdx.x;
    int t = threadIdx.x;
    int lane = t & 63, wid = t >> 6;
    int idx0 = b * SCAN_CHUNK + t * 4;
    int d[4];
    int s = 0;
    #pragma unroll
    for (int j = 0; j < 4; j++) {
        int idx = idx0 + j;
        d[j] = (idx < NN) ? deg[idx] : 0;
        s += d[j];
    }
    int inc = s;
    for (int o = 1; o < 64; o <<= 1) { int u = __shfl_up(inc, o, 64); if (lane >= o) inc += u; }
    if (lane == 63) wtot[wid] = inc;
    __syncthreads();
    int add = bpre[b];
    for (int w = 0; w < wid; w++) add += wtot[w];
    int excl = inc - s + add;
    #pragma unroll
    for (int j = 0; j < 4; j++) {
        int idx = idx0 + j;
        if (idx < NN) {
            rowptr[idx] = excl; cursor[idx] = excl;
            if (idx % BUCKN == 0) bcur[idx / BUCKN] = excl;   // bucket base
        }
        excl += d[j];
    }
}

// ---- pass 1: bin edges into 8 dst-range buckets (block-private windows -> L2-combinable writes) ----
__global__ void k_binA(const int* __restrict__ srcI, const int* __restrict__ dstI,
                       const float* __restrict__ ew, int* __restrict__ bcur,
                       int* __restrict__ bdst, int2* __restrict__ bse,
                       float* __restrict__ params) {
    __shared__ int hcnt[NBUCK], hbase[NBUCK], hoff[NBUCK];
    int t = threadIdx.x;
    int e0 = blockIdx.x * BIN_CHUNK;
    if (t < NBUCK) hcnt[t] = 0;
    __syncthreads();
    for (int i = t; i < BIN_CHUNK; i += 256) {
        int e = e0 + i;
        if (e < NE) atomicAdd(&hcnt[dstI[e] / BUCKN], 1);
    }
    __syncthreads();
    if (t < NBUCK) { hbase[t] = atomicAdd(&bcur[t], hcnt[t]); hoff[t] = 0; }
    __syncthreads();
    float locw = 0.f;
    for (int i = t; i < BIN_CHUNK; i += 256) {
        int e = e0 + i;
        if (e < NE) {
            int d = dstI[e];
            float w = ew[e];
            locw += w;
            int b = d / BUCKN;
            int p = hbase[b] + atomicAdd(&hoff[b], 1);
            bdst[p] = d;
            bse[p] = make_int2(srcI[e], __float_as_int(w));
        }
    }
    for (int o = 32; o > 0; o >>= 1) locw += __shfl_down(locw, o, 64);
    if ((t & 63) == 0) atomicAdd(&params[0], locw);
}

// ---- pass 2: scatter within bucket; bucket = blockIdx.x & 7 tracks round-robin block->XCD ----
__global__ void k_binB(const int* __restrict__ bdst, const int2* __restrict__ bse,
                       const int* __restrict__ rowptr, int* __restrict__ cursor,
                       int2* __restrict__ edge2) {
    int b = blockIdx.x & (NBUCK - 1);
    int slice = blockIdx.x >> 3;            // 0..255
    int lo = rowptr[b * BUCKN];
    int hi = rowptr[(b + 1) * BUCKN];
    int len = hi - lo;
    int per = (len + 255) / 256;
    int s0 = lo + slice * per;
    int s1 = min(s0 + per, hi);
    for (int i = s0 + threadIdx.x; i < s1; i += 256) {
        int d = bdst[i];
        int idx = atomicAdd(&cursor[d], 1);
        edge2[idx] = bse[i];
    }
}

// ---------------- Layer 1 GEMM: lane=row, wave=head(32 cols), x staged in LDS; xs1 out bf16 ----------------

__global__ void __launch_bounds__(256, 4)
k_gemm1(const float* __restrict__ x, const float* __restrict__ W1,
        const float* __restrict__ asv, const float* __restrict__ adv,
        unsigned* __restrict__ xs1b, float* __restrict__ as1, float* __restrict__ ad1) {
    __shared__ float xt[64 * 129];     // 64 rows, stride 129 (+1 pad -> 2-way bank = free)
    int t = threadIdx.x;
    int r0 = blockIdx.x * 64;
    for (int i = t; i < 2048; i += 256) {
        int row = i >> 5;           // 32 float4 per row
        int c4 = i & 31;
        float4 v = (r0 + row < NN) ? ((const float4*)x)[(size_t)(r0 + row) * 32 + c4]
                                   : make_float4(0.f, 0.f, 0.f, 0.f);
        float* dst = &xt[row * 129 + c4 * 4];
        dst[0] = v.x; dst[1] = v.y; dst[2] = v.z; dst[3] = v.w;
    }
    __syncthreads();
    int wid = t >> 6, lane = t & 63;
    int row = r0 + lane;
    int c0 = __builtin_amdgcn_readfirstlane(wid * 32);   // head = wid; uniform -> scalar W path
    float acc[32];
    #pragma unroll
    for (int c = 0; c < 32; c++) acc[c] = 0.f;
    const float* xr = &xt[lane * 129];
    const float* wp = W1 + c0;
    #pragma unroll 2
    for (int k = 0; k < 128; k++) {
        float xv = xr[k];
        const float* wk = wp + k * 128;
        #pragma unroll
        for (int c = 0; c < 32; c++) acc[c] += xv * wk[c];
    }
    if (row < NN) {
        unsigned* orow = xs1b + (size_t)row * 64 + wid * 16;
        #pragma unroll
        for (int j = 0; j < 4; j++) {
            uint4 pk;
            pk.x = pack2bf(acc[8*j+0], acc[8*j+1]);
            pk.y = pack2bf(acc[8*j+2], acc[8*j+3]);
            pk.z = pack2bf(acc[8*j+4], acc[8*j+5]);
            pk.w = pack2bf(acc[8*j+6], acc[8*j+7]);
            *(uint4*)(orow + 4*j) = pk;
        }
        float ps = 0.f, pd = 0.f;
        #pragma unroll
        for (int c = 0; c < 32; c++) { ps += acc[c] * asv[c0 + c]; pd += acc[c] * adv[c0 + c]; }
        as1[row * 4 + wid] = ps;
        ad1[row * 4 + wid] = pd;
    }
}

// ---------------- Layer 1 aggregation: bf16 gathers, fp32 softmax/accum, ELU ----------------

__global__ void k_agg1(const unsigned* __restrict__ xs1b, const float* __restrict__ as1,
                       const float* __restrict__ ad1, const int* __restrict__ rowptr,
                       const int2* __restrict__ edge2,
                       const float* __restrict__ params, const float* __restrict__ b1,
                       float* __restrict__ h1) {
    int wid = threadIdx.x >> 6, lane = threadIdx.x & 63;
    int n = blockIdx.x * 4 + wid;
    if (n >= NN) return;
    int h = lane >> 4;
    float ce = params[2 + h];
    float meanw = params[1];
    float adn = ad1[n * 4 + h];
    float aself = as1[n * 4 + h] + adn + meanw * ce;
    aself = aself > 0.f ? aself : NEG * aself;
    float p = __expf(aself);
    unsigned us = xs1b[(size_t)n * 64 + lane];
    float sx = __uint_as_float(us << 16);
    float sy = __uint_as_float(us & 0xFFFF0000u);
    float s0 = p, s1 = 0.f;
    float ax0 = p * sx, ay0 = p * sy, ax1 = 0.f, ay1 = 0.f;
    int lo = rowptr[n], hi = rowptr[n + 1];
    int i = lo;
    for (; i + 2 <= hi; i += 2) {
        int2 e0 = edge2[i], e1 = edge2[i + 1];
        float a0 = as1[e0.x * 4 + h] + adn + __int_as_float(e0.y) * ce;
        float a1 = as1[e1.x * 4 + h] + adn + __int_as_float(e1.y) * ce;
        a0 = a0 > 0.f ? a0 : NEG * a0;
        a1 = a1 > 0.f ? a1 : NEG * a1;
        float q0 = __expf(a0), q1 = __expf(a1);
        unsigned u0 = xs1b[(size_t)e0.x * 64 + lane];
        unsigned u1 = xs1b[(size_t)e1.x * 64 + lane];
        float v0x = __uint_as_float(u0 << 16), v0y = __uint_as_float(u0 & 0xFFFF0000u);
        float v1x = __uint_as_float(u1 << 16), v1y = __uint_as_float(u1 & 0xFFFF0000u);
        s0 += q0; s1 += q1;
        ax0 += q0 * v0x; ay0 += q0 * v0y;
        ax1 += q1 * v1x; ay1 += q1 * v1y;
    }
    if (i < hi) {
        int2 e0 = edge2[i];
        float a0 = as1[e0.x * 4 + h] + adn + __int_as_float(e0.y) * ce;
        a0 = a0 > 0.f ? a0 : NEG * a0;
        float q0 = __expf(a0);
        unsigned u0 = xs1b[(size_t)e0.x * 64 + lane];
        s0 += q0;
        ax0 += q0 * __uint_as_float(u0 << 16);
        ay0 += q0 * __uint_as_float(u0 & 0xFFFF0000u);
    }
    float inv = 1.0f / (s0 + s1 + 1e-16f);
    float o0 = (ax0 + ax1) * inv + b1[2 * lane];
    float o1 = (ay0 + ay1) * inv + b1[2 * lane + 1];
    o0 = o0 > 0.f ? o0 : (__expf(o0) - 1.0f);   // ELU
    o1 = o1 > 0.f ? o1 : (__expf(o1) - 1.0f);
    *(float2*)(h1 + (size_t)n * 128 + 2 * lane) = make_float2(o0, o1);
}

// ---------------- Layer 2 GEMM: lane=row, wave=16-col chunk, h1 staged in LDS; xs2 out bf16 ----------------

__global__ void __launch_bounds__(256, 4)
k_gemm2(const float* __restrict__ h1, const float* __restrict__ W2,
        const float* __restrict__ asv, const float* __restrict__ adv,
        unsigned* __restrict__ xs2b, float* __restrict__ as2, float* __restrict__ ad2) {
    __shared__ float xt[64 * 129];       // 33 KB
    __shared__ float pp[2][4][64];       // cross-wave alpha partials (2 KB)
    int t = threadIdx.x;
    int r0 = blockIdx.x * 64;
    for (int i = t; i < 2048; i += 256) {
        int row = i >> 5;
        int c4 = i & 31;
        float4 v = (r0 + row < NN) ? ((const float4*)h1)[(size_t)(r0 + row) * 32 + c4]
                                   : make_float4(0.f, 0.f, 0.f, 0.f);
        float* dst = &xt[row * 129 + c4 * 4];
        dst[0] = v.x; dst[1] = v.y; dst[2] = v.z; dst[3] = v.w;
    }
    __syncthreads();
    int wid = t >> 6, lane = t & 63;
    int row = r0 + lane;
    int c0 = __builtin_amdgcn_readfirstlane(wid * 16);
    float acc[16];
    #pragma unroll
    for (int c = 0; c < 16; c++) acc[c] = 0.f;
    const float* xr = &xt[lane * 129];
    const float* wp = W2 + c0;
    #pragma unroll 2
    for (int k = 0; k < 128; k++) {
        float xv = xr[k];
        const float* wk = wp + k * 64;
        #pragma unroll
        for (int c = 0; c < 16; c++) acc[c] += xv * wk[c];
    }
    float ps = 0.f, pd = 0.f;
    #pragma unroll
    for (int c = 0; c < 16; c++) { ps += acc[c] * asv[c0 + c]; pd += acc[c] * adv[c0 + c]; }
    pp[0][wid][lane] = ps;
    pp[1][wid][lane] = pd;
    if (row < NN) {
        unsigned* orow = xs2b + (size_t)row * 32 + wid * 8;
        #pragma unroll
        for (int j = 0; j < 2; j++) {
            uint4 pk;
            pk.x = pack2bf(acc[8*j+0], acc[8*j+1]);
            pk.y = pack2bf(acc[8*j+2], acc[8*j+3]);
            pk.z = pack2bf(acc[8*j+4], acc[8*j+5]);
            pk.w = pack2bf(acc[8*j+6], acc[8*j+7]);
            *(uint4*)(orow + 4*j) = pk;
        }
    }
    __syncthreads();
    if (wid == 0 && row < NN) {
        as2[row] = pp[0][0][lane] + pp[0][1][lane] + pp[0][2][lane] + pp[0][3][lane];
        ad2[row] = pp[1][0][lane] + pp[1][1][lane] + pp[1][2][lane] + pp[1][3][lane];
    }
}

// ---------------- Layer 2 aggregation: bf16 gathers (ushort/lane) ----------------

__global__ void k_agg2(const unsigned short* __restrict__ xs2h, const float* __restrict__ as2,
                       const float* __restrict__ ad2, const int* __restrict__ rowptr,
                       const int2* __restrict__ edge2,
                       const float* __restrict__ params, const float* __restrict__ b2,
                       float* __restrict__ out) {
    int wid = threadIdx.x >> 6, lane = threadIdx.x & 63;
    int n = blockIdx.x * 4 + wid;
    if (n >= NN) return;
    float ce = params[6];
    float meanw = params[1];
    float adn = ad2[n];
    float aself = as2[n] + adn + meanw * ce;
    aself = aself > 0.f ? aself : NEG * aself;
    float p = __expf(aself);
    float sv = __uint_as_float(((unsigned)xs2h[(size_t)n * 64 + lane]) << 16);
    float s0 = p, s1 = 0.f;
    float ac0 = p * sv, ac1 = 0.f;
    int lo = rowptr[n], hi = rowptr[n + 1];
    int i = lo;
    for (; i + 2 <= hi; i += 2) {
        int2 e0 = edge2[i], e1 = edge2[i + 1];
        float a0 = as2[e0.x] + adn + __int_as_float(e0.y) * ce;
        float a1 = as2[e1.x] + adn + __int_as_float(e1.y) * ce;
        a0 = a0 > 0.f ? a0 : NEG * a0;
        a1 = a1 > 0.f ? a1 : NEG * a1;
        float q0 = __expf(a0), q1 = __expf(a1);
        float v0 = __uint_as_float(((unsigned)xs2h[(size_t)e0.x * 64 + lane]) << 16);
        float v1 = __uint_as_float(((unsigned)xs2h[(size_t)e1.x * 64 + lane]) << 16);
        s0 += q0; s1 += q1;
        ac0 += q0 * v0; ac1 += q1 * v1;
    }
    if (i < hi) {
        int2 e0 = edge2[i];
        float a0 = as2[e0.x] + adn + __int_as_float(e0.y) * ce;
        a0 = a0 > 0.f ? a0 : NEG * a0;
        float q0 = __expf(a0);
        s0 += q0;
        ac0 += q0 * __uint_as_float(((unsigned)xs2h[(size_t)e0.x * 64 + lane]) << 16);
    }
    out[(size_t)n * 64 + lane] = (ac0 + ac1) / (s0 + s1 + 1e-16f) + b2[lane];
}

extern "C" void kernel_launch(void* const* d_in, const int* in_sizes, int n_in,
                              void* d_out, int out_size, void* d_ws, size_t ws_size,
                              hipStream_t stream) {
    const float* x    = (const float*)d_in[0];
    const int*   ei   = (const int*)d_in[1];
    const float* ew   = (const float*)d_in[2];
    const float* W1   = (const float*)d_in[3];
    const float* as1v = (const float*)d_in[4];
    const float* ad1v = (const float*)d_in[5];
    const float* ae1v = (const float*)d_in[6];
    const float* We1  = (const float*)d_in[7];
    const float* b1   = (const float*)d_in[8];
    const float* W2   = (const float*)d_in[9];
    const float* as2v = (const float*)d_in[10];
    const float* ad2v = (const float*)d_in[11];
    const float* ae2v = (const float*)d_in[12];
    const float* We2  = (const float*)d_in[13];
    const float* b2   = (const float*)d_in[14];
    const int* srcI = ei;
    const int* dstI = ei + NE;

    float* wsf = (float*)d_ws;
    size_t off = 0;
    auto alloc = [&](size_t nelts) { float* p = wsf + off; off += (nelts + 63) & ~(size_t)63; return p; };
    float*    params = alloc(64);
    int*      deg    = (int*)alloc(NN);
    int*      rowptr = (int*)alloc(NN + 1);
    int*      cursor = (int*)alloc(NN);
    int*      bsum   = (int*)alloc(NBLK);
    int*      bpre   = (int*)alloc(NBLK);
    int*      bcur   = (int*)alloc(NBUCK);
    int*      bdst   = (int*)alloc(NE);
    int2*     bse    = (int2*)alloc((size_t)NE * 2);
    int2*     edge2  = (int2*)alloc((size_t)NE * 2);
    float*    as1    = alloc(NN * 4);
    float*    ad1    = alloc(NN * 4);
    unsigned* xs1b   = (unsigned*)alloc((size_t)NN * 64);   // bf16 [N][128]
    float*    h1     = alloc((size_t)NN * 128);
    unsigned* xs2b   = xs1b;   // layer-2 reuses (xs1b dead after k_agg1)
    float*    as2 = as1;
    float*    ad2 = ad1;

    hipMemsetAsync(d_ws, 0, (64 + NN + 64) * sizeof(float), stream);

    k_hist <<<2048, 256, 0, stream>>>(dstI, deg);
    k_scanA<<<NBLK, 256, 0, stream>>>(deg, bsum);
    k_scanB<<<1, 128, 0, stream>>>(bsum, bpre, rowptr);
    k_scanC<<<NBLK, 256, 0, stream>>>(deg, bpre, rowptr, cursor, bcur);
    k_binA <<<NBINBLK, 256, 0, stream>>>(srcI, dstI, ew, bcur, bdst, bse, params);
    k_setup<<<1, 128, 0, stream>>>(We1, ae1v, We2, ae2v, params);
    k_binB <<<2048, 256, 0, stream>>>(bdst, bse, rowptr, cursor, edge2);
    k_gemm1<<<(NN + 63) / 64, 256, 0, stream>>>(x, W1, as1v, ad1v, xs1b, as1, ad1);
    k_agg1 <<<25000, 256, 0, stream>>>(xs1b, as1, ad1, rowptr, edge2, params, b1, h1);
    k_gemm2<<<(NN + 63) / 64, 256, 0, stream>>>(h1, W2, as2v, ad2v, xs2b, as2, ad2);
    k_agg2 <<<25000, 256, 0, stream>>>((const unsigned short*)xs2b, as2, ad2, rowptr, edge2, params, b2, (float*)d_out);
}

// Round 8
// 498.516 us; speedup vs baseline: 2.5789x; 1.0338x over previous
//
#include <hip/hip_runtime.h>
#include <math.h>

#define NN 100000
#define NE 1600000
#define DIN 128
#define NH 4
#define C1 32
#define C2 64
#define NEG 0.2f

#define SCAN_CHUNK 1024
#define NBLK ((NN + SCAN_CHUNK - 1) / SCAN_CHUNK)   // 98

#define NBUCK 8
#define BUCKN (NN / NBUCK)          // 12500 nodes per bucket
#define CAPB 300000                 // fixed bucket capacity (uniform dst -> ~200K each)
#define BIN_CHUNK 4096
#define NBINBLK ((NE + BIN_CHUNK - 1) / BIN_CHUNK)  // 391

__device__ __forceinline__ unsigned bf16rtn(float f) {
    unsigned b = __float_as_uint(f);
    return (b + 0x7FFFu + ((b >> 16) & 1u)) >> 16;
}
__device__ __forceinline__ unsigned pack2bf(float lo, float hi) {
    return bf16rtn(lo) | (bf16rtn(hi) << 16);
}

__global__ void k_setup(const float* __restrict__ We1, const float* __restrict__ ae1,
                        const float* __restrict__ We2, const float* __restrict__ ae2,
                        float* __restrict__ params) {
    __shared__ float sm[128];
    int t = threadIdx.x;
    sm[t] = We1[t] * ae1[t];
    __syncthreads();
    if (t < 4) {
        float s = 0.f;
        for (int c = 0; c < 32; c++) s += sm[t * 32 + c];
        params[2 + t] = s;            // ce1[h]
    }
    __syncthreads();
    if (t < 64) sm[t] = We2[t] * ae2[t];
    __syncthreads();
    if (t == 0) {
        float s = 0.f;
        for (int c = 0; c < 64; c++) s += sm[c];
        params[6] = s;                // ce2
        params[1] = params[0] / (float)NE;  // mean edge weight
    }
}

// ---- pass 1: bin edges into 8 dst-range buckets (fixed-capacity regions) ----
__global__ void k_binA(const int* __restrict__ srcI, const int* __restrict__ dstI,
                       const float* __restrict__ ew, int* __restrict__ bcur,
                       int* __restrict__ bdst, int2* __restrict__ bse,
                       float* __restrict__ params) {
    __shared__ int hcnt[NBUCK], hbase[NBUCK], hoff[NBUCK];
    int t = threadIdx.x;
    int e0 = blockIdx.x * BIN_CHUNK;
    if (t < NBUCK) hcnt[t] = 0;
    __syncthreads();
    for (int i = t; i < BIN_CHUNK; i += 256) {
        int e = e0 + i;
        if (e < NE) atomicAdd(&hcnt[dstI[e] / BUCKN], 1);
    }
    __syncthreads();
    if (t < NBUCK) { hbase[t] = atomicAdd(&bcur[t], hcnt[t]); hoff[t] = 0; }
    __syncthreads();
    float locw = 0.f;
    for (int i = t; i < BIN_CHUNK; i += 256) {
        int e = e0 + i;
        if (e < NE) {
            int d = dstI[e];
            float w = ew[e];
            locw += w;
            int b = d / BUCKN;
            int p = b * CAPB + hbase[b] + atomicAdd(&hoff[b], 1);
            bdst[p] = d;
            bse[p] = make_int2(srcI[e], __float_as_int(w));
        }
    }
    for (int o = 32; o > 0; o >>= 1) locw += __shfl_down(locw, o, 64);
    if ((t & 63) == 0) atomicAdd(&params[0], locw);
}

// ---- per-node degree histogram, XCD-local per bucket ----
__global__ void k_histB(const int* __restrict__ bdst, const int* __restrict__ bcur,
                        int* __restrict__ deg) {
    int b = blockIdx.x & (NBUCK - 1);
    int slice = blockIdx.x >> 3;
    int cnt = bcur[b];
    int lo = b * CAPB;
    int per = (cnt + 255) / 256;
    int s0 = lo + slice * per;
    int s1 = min(s0 + per, lo + cnt);
    for (int i = s0 + threadIdx.x; i < s1; i += 256)
        atomicAdd(&deg[bdst[i]], 1);
}

// block partial sums
__global__ void k_scanA(const int* __restrict__ deg, int* __restrict__ bsum) {
    __shared__ int ws[4];
    int b = blockIdx.x;
    int base = b * SCAN_CHUNK;
    int t = threadIdx.x;
    int s = 0;
    for (int i = t; i < SCAN_CHUNK; i += 256) {
        int idx = base + i;
        if (idx < NN) s += deg[idx];
    }
    for (int o = 32; o > 0; o >>= 1) s += __shfl_down(s, o, 64);
    int lane = t & 63, wid = t >> 6;
    if (lane == 0) ws[wid] = s;
    __syncthreads();
    if (t == 0) bsum[b] = ws[0] + ws[1] + ws[2] + ws[3];
}

__global__ void k_scanB(const int* __restrict__ bsum, int* __restrict__ bpre,
                        int* __restrict__ rowptr) {
    __shared__ int wtot[2];
    int t = threadIdx.x;
    int lane = t & 63, wid = t >> 6;
    int v = (t < NBLK) ? bsum[t] : 0;
    int inc = v;
    for (int o = 1; o < 64; o <<= 1) { int u = __shfl_up(inc, o, 64); if (lane >= o) inc += u; }
    if (lane == 63) wtot[wid] = inc;
    __syncthreads();
    if (wid == 1) inc += wtot[0];
    if (t < NBLK) bpre[t] = inc - v;          // exclusive prefix
    if (t == NBLK - 1) rowptr[NN] = inc;      // total == NE
}

__global__ void k_scanC(const int* __restrict__ deg, const int* __restrict__ bpre,
                        int* __restrict__ rowptr, int* __restrict__ cursor) {
    __shared__ int wtot[4];
    int b = blockIdx.x;
    int t = threadIdx.x;
    int lane = t & 63, wid = t >> 6;
    int idx0 = b * SCAN_CHUNK + t * 4;
    int d[4];
    int s = 0;
    #pragma unroll
    for (int j = 0; j < 4; j++) {
        int idx = idx0 + j;
        d[j] = (idx < NN) ? deg[idx] : 0;
        s += d[j];
    }
    int inc = s;
    for (int o = 1; o < 64; o <<= 1) { int u = __shfl_up(inc, o, 64); if (lane >= o) inc += u; }
    if (lane == 63) wtot[wid] = inc;
    __syncthreads();
    int add = bpre[b];
    for (int w = 0; w < wid; w++) add += wtot[w];
    int excl = inc - s + add;
    #pragma unroll
    for (int j = 0; j < 4; j++) {
        int idx = idx0 + j;
        if (idx < NN) { rowptr[idx] = excl; cursor[idx] = excl; }
        excl += d[j];
    }
}

// ---- pass 2: scatter within bucket; bucket = blockIdx.x & 7 tracks round-robin block->XCD ----
__global__ void k_binB(const int* __restrict__ bdst, const int2* __restrict__ bse,
                       const int* __restrict__ bcur, int* __restrict__ cursor,
                       int2* __restrict__ edge2) {
    int b = blockIdx.x & (NBUCK - 1);
    int slice = blockIdx.x >> 3;
    int cnt = bcur[b];
    int lo = b * CAPB;
    int per = (cnt + 255) / 256;
    int s0 = lo + slice * per;
    int s1 = min(s0 + per, lo + cnt);
    for (int i = s0 + threadIdx.x; i < s1; i += 256) {
        int d = bdst[i];
        int idx = atomicAdd(&cursor[d], 1);
        edge2[idx] = bse[i];
    }
}

// ---------------- Layer 1 GEMM: lane=row, wave=head(32 cols), x staged in LDS; xs1 out bf16 ----------------

__global__ void __launch_bounds__(256, 4)
k_gemm1(const float* __restrict__ x, const float* __restrict__ W1,
        const float* __restrict__ asv, const float* __restrict__ adv,
        unsigned* __restrict__ xs1b, float* __restrict__ as1, float* __restrict__ ad1) {
    __shared__ float xt[64 * 129];
    int t = threadIdx.x;
    int r0 = blockIdx.x * 64;
    for (int i = t; i < 2048; i += 256) {
        int row = i >> 5;
        int c4 = i & 31;
        float4 v = (r0 + row < NN) ? ((const float4*)x)[(size_t)(r0 + row) * 32 + c4]
                                   : make_float4(0.f, 0.f, 0.f, 0.f);
        float* dst = &xt[row * 129 + c4 * 4];
        dst[0] = v.x; dst[1] = v.y; dst[2] = v.z; dst[3] = v.w;
    }
    __syncthreads();
    int wid = t >> 6, lane = t & 63;
    int row = r0 + lane;
    int c0 = __builtin_amdgcn_readfirstlane(wid * 32);
    float acc[32];
    #pragma unroll
    for (int c = 0; c < 32; c++) acc[c] = 0.f;
    const float* xr = &xt[lane * 129];
    const float* wp = W1 + c0;
    #pragma unroll 2
    for (int k = 0; k < 128; k++) {
        float xv = xr[k];
        const float* wk = wp + k * 128;
        #pragma unroll
        for (int c = 0; c < 32; c++) acc[c] += xv * wk[c];
    }
    if (row < NN) {
        unsigned* orow = xs1b + (size_t)row * 64 + wid * 16;
        #pragma unroll
        for (int j = 0; j < 4; j++) {
            uint4 pk;
            pk.x = pack2bf(acc[8*j+0], acc[8*j+1]);
            pk.y = pack2bf(acc[8*j+2], acc[8*j+3]);
            pk.z = pack2bf(acc[8*j+4], acc[8*j+5]);
            pk.w = pack2bf(acc[8*j+6], acc[8*j+7]);
            *(uint4*)(orow + 4*j) = pk;
        }
        float ps = 0.f, pd = 0.f;
        #pragma unroll
        for (int c = 0; c < 32; c++) { ps += acc[c] * asv[c0 + c]; pd += acc[c] * adv[c0 + c]; }
        as1[row * 4 + wid] = ps;
        ad1[row * 4 + wid] = pd;
    }
}

// ---------------- Layer 1 aggregation: phase-split (lane-parallel alpha, shfl-broadcast PV) ----------------

__global__ void k_agg1(const unsigned* __restrict__ xs1b, const float* __restrict__ as1,
                       const float* __restrict__ ad1, const int* __restrict__ rowptr,
                       const int2* __restrict__ edge2,
                       const float* __restrict__ params, const float* __restrict__ b1,
                       float* __restrict__ h1) {
    int wid = threadIdx.x >> 6, lane = threadIdx.x & 63;
    int n = blockIdx.x * 4 + wid;
    if (n >= NN) return;
    int h4 = lane & 3;          // head owned in phase 1
    int h  = lane >> 4;         // head mapped to channels in phase 2
    float ceP  = params[2 + h4];
    float adnP = ad1[n * 4 + h4];
    // self loop
    float meanw = params[1];
    float aself = as1[n * 4 + h] + ad1[n * 4 + h] + meanw * params[2 + h];
    aself = aself > 0.f ? aself : NEG * aself;
    float qs = __expf(aself);
    unsigned us = xs1b[(size_t)n * 64 + lane];
    float s  = qs;
    float ax = qs * __uint_as_float(us << 16);
    float ay = qs * __uint_as_float(us & 0xFFFF0000u);
    int lo = rowptr[n], hi = rowptr[n + 1];
    for (int base = lo; base < hi; base += 16) {
        // phase 1: lane (e,h4) computes q for edge base+e, head h4
        int e = lane >> 2;
        int idx = base + e;
        int cx = 0;
        float q = 0.f;
        if (idx < hi) {
            int2 cv = edge2[idx];
            cx = cv.x;
            float a = as1[cx * 4 + h4] + adnP + __int_as_float(cv.y) * ceP;
            a = a > 0.f ? a : NEG * a;
            q = __expf(a);
        }
        int m = hi - base; if (m > 16) m = 16;
        // phase 2: broadcast (c,q), gather row, accumulate
        #define STEP1(j) { \
            int cj = __shfl(cx, 4*(j), 64); \
            float qj = __shfl(q, 4*(j) + h, 64); \
            unsigned u = xs1b[(size_t)cj * 64 + lane]; \
            s += qj; \
            ax += qj * __uint_as_float(u << 16); \
            ay += qj * __uint_as_float(u & 0xFFFF0000u); }
        if (m == 16) {
            #pragma unroll
            for (int j = 0; j < 16; j++) STEP1(j)
        } else {
            for (int j = 0; j < m; j++) STEP1(j)
        }
        #undef STEP1
    }
    float inv = 1.0f / (s + 1e-16f);
    float o0 = ax * inv + b1[2 * lane];
    float o1 = ay * inv + b1[2 * lane + 1];
    o0 = o0 > 0.f ? o0 : (__expf(o0) - 1.0f);   // ELU
    o1 = o1 > 0.f ? o1 : (__expf(o1) - 1.0f);
    *(float2*)(h1 + (size_t)n * 128 + 2 * lane) = make_float2(o0, o1);
}

// ---------------- Layer 2 GEMM: lane=row, wave=16-col chunk, h1 staged in LDS; xs2 out bf16 ----------------

__global__ void __launch_bounds__(256, 4)
k_gemm2(const float* __restrict__ h1, const float* __restrict__ W2,
        const float* __restrict__ asv, const float* __restrict__ adv,
        unsigned* __restrict__ xs2b, float* __restrict__ as2, float* __restrict__ ad2) {
    __shared__ float xt[64 * 129];
    __shared__ float pp[2][4][64];
    int t = threadIdx.x;
    int r0 = blockIdx.x * 64;
    for (int i = t; i < 2048; i += 256) {
        int row = i >> 5;
        int c4 = i & 31;
        float4 v = (r0 + row < NN) ? ((const float4*)h1)[(size_t)(r0 + row) * 32 + c4]
                                   : make_float4(0.f, 0.f, 0.f, 0.f);
        float* dst = &xt[row * 129 + c4 * 4];
        dst[0] = v.x; dst[1] = v.y; dst[2] = v.z; dst[3] = v.w;
    }
    __syncthreads();
    int wid = t >> 6, lane = t & 63;
    int row = r0 + lane;
    int c0 = __builtin_amdgcn_readfirstlane(wid * 16);
    float acc[16];
    #pragma unroll
    for (int c = 0; c < 16; c++) acc[c] = 0.f;
    const float* xr = &xt[lane * 129];
    const float* wp = W2 + c0;
    #pragma unroll 2
    for (int k = 0; k < 128; k++) {
        float xv = xr[k];
        const float* wk = wp + k * 64;
        #pragma unroll
        for (int c = 0; c < 16; c++) acc[c] += xv * wk[c];
    }
    float ps = 0.f, pd = 0.f;
    #pragma unroll
    for (int c = 0; c < 16; c++) { ps += acc[c] * asv[c0 + c]; pd += acc[c] * adv[c0 + c]; }
    pp[0][wid][lane] = ps;
    pp[1][wid][lane] = pd;
    if (row < NN) {
        unsigned* orow = xs2b + (size_t)row * 32 + wid * 8;
        #pragma unroll
        for (int j = 0; j < 2; j++) {
            uint4 pk;
            pk.x = pack2bf(acc[8*j+0], acc[8*j+1]);
            pk.y = pack2bf(acc[8*j+2], acc[8*j+3]);
            pk.z = pack2bf(acc[8*j+4], acc[8*j+5]);
            pk.w = pack2bf(acc[8*j+6], acc[8*j+7]);
            *(uint4*)(orow + 4*j) = pk;
        }
    }
    __syncthreads();
    if (wid == 0 && row < NN) {
        as2[row] = pp[0][0][lane] + pp[0][1][lane] + pp[0][2][lane] + pp[0][3][lane];
        ad2[row] = pp[1][0][lane] + pp[1][1][lane] + pp[1][2][lane] + pp[1][3][lane];
    }
}

// ---------------- Layer 2 aggregation: phase-split ----------------

__global__ void k_agg2(const unsigned short* __restrict__ xs2h, const float* __restrict__ as2,
                       const float* __restrict__ ad2, const int* __restrict__ rowptr,
                       const int2* __restrict__ edge2,
                       const float* __restrict__ params, const float* __restrict__ b2,
                       float* __restrict__ out) {
    int wid = threadIdx.x >> 6, lane = threadIdx.x & 63;
    int n = blockIdx.x * 4 + wid;
    if (n >= NN) return;
    float ce = params[6];
    float meanw = params[1];
    float adn = ad2[n];
    float aself = as2[n] + adn + meanw * ce;
    aself = aself > 0.f ? aself : NEG * aself;
    float qs = __expf(aself);
    float s = qs;
    float ac = qs * __uint_as_float(((unsigned)xs2h[(size_t)n * 64 + lane]) << 16);
    int lo = rowptr[n], hi = rowptr[n + 1];
    for (int base = lo; base < hi; base += 64) {
        int idx = base + lane;
        int cx = 0;
        float q = 0.f;
        if (idx < hi) {
            int2 cv = edge2[idx];
            cx = cv.x;
            float a = as2[cx] + adn + __int_as_float(cv.y) * ce;
            a = a > 0.f ? a : NEG * a;
            q = __expf(a);
        }
        int m = hi - base; if (m > 64) m = 64;
        #pragma unroll 4
        for (int j = 0; j < m; j++) {
            int cj = __shfl(cx, j, 64);
            float qj = __shfl(q, j, 64);
            float v = __uint_as_float(((unsigned)xs2h[(size_t)cj * 64 + lane]) << 16);
            s += qj;
            ac += qj * v;
        }
    }
    out[(size_t)n * 64 + lane] = ac / (s + 1e-16f) + b2[lane];
}

extern "C" void kernel_launch(void* const* d_in, const int* in_sizes, int n_in,
                              void* d_out, int out_size, void* d_ws, size_t ws_size,
                              hipStream_t stream) {
    const float* x    = (const float*)d_in[0];
    const int*   ei   = (const int*)d_in[1];
    const float* ew   = (const float*)d_in[2];
    const float* W1   = (const float*)d_in[3];
    const float* as1v = (const float*)d_in[4];
    const float* ad1v = (const float*)d_in[5];
    const float* ae1v = (const float*)d_in[6];
    const float* We1  = (const float*)d_in[7];
    const float* b1   = (const float*)d_in[8];
    const float* W2   = (const float*)d_in[9];
    const float* as2v = (const float*)d_in[10];
    const float* ad2v = (const float*)d_in[11];
    const float* ae2v = (const float*)d_in[12];
    const float* We2  = (const float*)d_in[13];
    const float* b2   = (const float*)d_in[14];
    const int* srcI = ei;
    const int* dstI = ei + NE;

    float* wsf = (float*)d_ws;
    size_t off = 0;
    auto alloc = [&](size_t nelts) { float* p = wsf + off; off += (nelts + 63) & ~(size_t)63; return p; };
    float*    params = alloc(64);
    int*      deg    = (int*)alloc(NN);            // padded to 100032
    int*      bcur   = (int*)alloc(64);
    int*      rowptr = (int*)alloc(NN + 1);
    int*      cursor = (int*)alloc(NN);
    int*      bsum   = (int*)alloc(NBLK);
    int*      bpre   = (int*)alloc(NBLK);
    size_t    binsOff = off;
    int*      bdst   = (int*)alloc((size_t)NBUCK * CAPB);        // 2.4M ints
    int2*     bse    = (int2*)alloc((size_t)NBUCK * CAPB * 2);   // 4.8M ints
    int2*     edge2  = (int2*)alloc((size_t)NE * 2);
    float*    as1    = alloc(NN * 4);
    float*    ad1    = alloc(NN * 4);
    float*    h1     = alloc((size_t)NN * 128);
    // xs1b overlays the bin region (bdst+bse = 7.2M words >= 6.4M; bins dead before gemm1)
    unsigned* xs1b   = (unsigned*)(wsf + binsOff);
    unsigned* xs2b   = xs1b;
    float*    as2 = as1;
    float*    ad2 = ad1;

    // zero params + deg + bcur (contiguous at ws start)
    hipMemsetAsync(d_ws, 0, (64 + 100032 + 64) * sizeof(float), stream);

    k_binA <<<NBINBLK, 256, 0, stream>>>(srcI, dstI, ew, bcur, bdst, bse, params);
    k_histB<<<2048, 256, 0, stream>>>(bdst, bcur, deg);
    k_scanA<<<NBLK, 256, 0, stream>>>(deg, bsum);
    k_scanB<<<1, 128, 0, stream>>>(bsum, bpre, rowptr);
    k_scanC<<<NBLK, 256, 0, stream>>>(deg, bpre, rowptr, cursor);
    k_binB <<<2048, 256, 0, stream>>>(bdst, bse, bcur, cursor, edge2);
    k_setup<<<1, 128, 0, stream>>>(We1, ae1v, We2, ae2v, params);
    k_gemm1<<<(NN + 63) / 64, 256, 0, stream>>>(x, W1, as1v, ad1v, xs1b, as1, ad1);
    k_agg1 <<<25000, 256, 0, stream>>>(xs1b, as1, ad1, rowptr, edge2, params, b1, h1);
    k_gemm2<<<(NN + 63) / 64, 256, 0, stream>>>(h1, W2, as2v, ad2v, xs2b, as2, ad2);
    k_agg2 <<<25000, 256, 0, stream>>>((const unsigned short*)xs2b, as2, ad2, rowptr, edge2, params, b2, (float*)d_out);
}

// Round 9
// 450.170 us; speedup vs baseline: 2.8559x; 1.1074x over previous
//
#include <hip/hip_runtime.h>
#include <math.h>

#define NN 100000
#define NE 1600000
#define DIN 128
#define NH 4
#define C1 32
#define C2 64
#define NEG 0.2f

#define SCAN_CHUNK 1024
#define NBLK ((NN + SCAN_CHUNK - 1) / SCAN_CHUNK)   // 98

#define NBUCK 8
#define BUCKN (NN / NBUCK)          // 12500 nodes per bucket
#define CAPB 300000                 // fixed bucket capacity (uniform dst -> ~200K each)
#define BIN_CHUNK 4096
#define NBINBLK ((NE + BIN_CHUNK - 1) / BIN_CHUNK)  // 391

__device__ __forceinline__ unsigned bf16rtn(float f) {
    unsigned b = __float_as_uint(f);
    return (b + 0x7FFFu + ((b >> 16) & 1u)) >> 16;
}
__device__ __forceinline__ unsigned pack2bf(float lo, float hi) {
    return bf16rtn(lo) | (bf16rtn(hi) << 16);
}

__global__ void k_setup(const float* __restrict__ We1, const float* __restrict__ ae1,
                        const float* __restrict__ We2, const float* __restrict__ ae2,
                        float* __restrict__ params) {
    __shared__ float sm[128];
    int t = threadIdx.x;
    sm[t] = We1[t] * ae1[t];
    __syncthreads();
    if (t < 4) {
        float s = 0.f;
        for (int c = 0; c < 32; c++) s += sm[t * 32 + c];
        params[2 + t] = s;            // ce1[h]
    }
    __syncthreads();
    if (t < 64) sm[t] = We2[t] * ae2[t];
    __syncthreads();
    if (t == 0) {
        float s = 0.f;
        for (int c = 0; c < 64; c++) s += sm[c];
        params[6] = s;                // ce2
        params[1] = params[0] / (float)NE;  // mean edge weight
    }
}

// ---- pass 1: bin edges into 8 dst-range buckets (fixed-capacity regions) ----
__global__ void k_binA(const int* __restrict__ srcI, const int* __restrict__ dstI,
                       const float* __restrict__ ew, int* __restrict__ bcur,
                       int* __restrict__ bdst, int2* __restrict__ bse,
                       float* __restrict__ params) {
    __shared__ int hcnt[NBUCK], hbase[NBUCK], hoff[NBUCK];
    int t = threadIdx.x;
    int e0 = blockIdx.x * BIN_CHUNK;
    if (t < NBUCK) hcnt[t] = 0;
    __syncthreads();
    for (int i = t; i < BIN_CHUNK; i += 256) {
        int e = e0 + i;
        if (e < NE) atomicAdd(&hcnt[dstI[e] / BUCKN], 1);
    }
    __syncthreads();
    if (t < NBUCK) { hbase[t] = atomicAdd(&bcur[t], hcnt[t]); hoff[t] = 0; }
    __syncthreads();
    float locw = 0.f;
    for (int i = t; i < BIN_CHUNK; i += 256) {
        int e = e0 + i;
        if (e < NE) {
            int d = dstI[e];
            float w = ew[e];
            locw += w;
            int b = d / BUCKN;
            int p = b * CAPB + hbase[b] + atomicAdd(&hoff[b], 1);
            bdst[p] = d;
            bse[p] = make_int2(srcI[e], __float_as_int(w));
        }
    }
    for (int o = 32; o > 0; o >>= 1) locw += __shfl_down(locw, o, 64);
    if ((t & 63) == 0) atomicAdd(&params[0], locw);
}

// ---- per-node degree histogram, XCD-local per bucket ----
__global__ void k_histB(const int* __restrict__ bdst, const int* __restrict__ bcur,
                        int* __restrict__ deg) {
    int b = blockIdx.x & (NBUCK - 1);
    int slice = blockIdx.x >> 3;
    int cnt = bcur[b];
    int lo = b * CAPB;
    int per = (cnt + 255) / 256;
    int s0 = lo + slice * per;
    int s1 = min(s0 + per, lo + cnt);
    for (int i = s0 + threadIdx.x; i < s1; i += 256)
        atomicAdd(&deg[bdst[i]], 1);
}

// block partial sums
__global__ void k_scanA(const int* __restrict__ deg, int* __restrict__ bsum) {
    __shared__ int ws[4];
    int b = blockIdx.x;
    int base = b * SCAN_CHUNK;
    int t = threadIdx.x;
    int s = 0;
    for (int i = t; i < SCAN_CHUNK; i += 256) {
        int idx = base + i;
        if (idx < NN) s += deg[idx];
    }
    for (int o = 32; o > 0; o >>= 1) s += __shfl_down(s, o, 64);
    int lane = t & 63, wid = t >> 6;
    if (lane == 0) ws[wid] = s;
    __syncthreads();
    if (t == 0) bsum[b] = ws[0] + ws[1] + ws[2] + ws[3];
}

__global__ void k_scanB(const int* __restrict__ bsum, int* __restrict__ bpre,
                        int* __restrict__ rowptr) {
    __shared__ int wtot[2];
    int t = threadIdx.x;
    int lane = t & 63, wid = t >> 6;
    int v = (t < NBLK) ? bsum[t] : 0;
    int inc = v;
    for (int o = 1; o < 64; o <<= 1) { int u = __shfl_up(inc, o, 64); if (lane >= o) inc += u; }
    if (lane == 63) wtot[wid] = inc;
    __syncthreads();
    if (wid == 1) inc += wtot[0];
    if (t < NBLK) bpre[t] = inc - v;          // exclusive prefix
    if (t == NBLK - 1) rowptr[NN] = inc;      // total == NE
}

__global__ void k_scanC(const int* __restrict__ deg, const int* __restrict__ bpre,
                        int* __restrict__ rowptr, int* __restrict__ cursor) {
    __shared__ int wtot[4];
    int b = blockIdx.x;
    int t = threadIdx.x;
    int lane = t & 63, wid = t >> 6;
    int idx0 = b * SCAN_CHUNK + t * 4;
    int d[4];
    int s = 0;
    #pragma unroll
    for (int j = 0; j < 4; j++) {
        int idx = idx0 + j;
        d[j] = (idx < NN) ? deg[idx] : 0;
        s += d[j];
    }
    int inc = s;
    for (int o = 1; o < 64; o <<= 1) { int u = __shfl_up(inc, o, 64); if (lane >= o) inc += u; }
    if (lane == 63) wtot[wid] = inc;
    __syncthreads();
    int add = bpre[b];
    for (int w = 0; w < wid; w++) add += wtot[w];
    int excl = inc - s + add;
    #pragma unroll
    for (int j = 0; j < 4; j++) {
        int idx = idx0 + j;
        if (idx < NN) { rowptr[idx] = excl; cursor[idx] = excl; }
        excl += d[j];
    }
}

// ---- pass 2: scatter within bucket; bucket = blockIdx.x & 7 tracks round-robin block->XCD ----
__global__ void k_binB(const int* __restrict__ bdst, const int2* __restrict__ bse,
                       const int* __restrict__ bcur, int* __restrict__ cursor,
                       int2* __restrict__ edge2) {
    int b = blockIdx.x & (NBUCK - 1);
    int slice = blockIdx.x >> 3;
    int cnt = bcur[b];
    int lo = b * CAPB;
    int per = (cnt + 255) / 256;
    int s0 = lo + slice * per;
    int s1 = min(s0 + per, lo + cnt);
    for (int i = s0 + threadIdx.x; i < s1; i += 256) {
        int d = bdst[i];
        int idx = atomicAdd(&cursor[d], 1);
        edge2[idx] = bse[i];
    }
}

// ---------------- Layer 1 GEMM: lane=row, wave=head(32 cols), x staged in LDS; xs1 out bf16 ----------------

__global__ void __launch_bounds__(256, 4)
k_gemm1(const float* __restrict__ x, const float* __restrict__ W1,
        const float* __restrict__ asv, const float* __restrict__ adv,
        unsigned* __restrict__ xs1b, float* __restrict__ as1, float* __restrict__ ad1) {
    __shared__ float xt[64 * 129];
    int t = threadIdx.x;
    int r0 = blockIdx.x * 64;
    for (int i = t; i < 2048; i += 256) {
        int row = i >> 5;
        int c4 = i & 31;
        float4 v = (r0 + row < NN) ? ((const float4*)x)[(size_t)(r0 + row) * 32 + c4]
                                   : make_float4(0.f, 0.f, 0.f, 0.f);
        float* dst = &xt[row * 129 + c4 * 4];
        dst[0] = v.x; dst[1] = v.y; dst[2] = v.z; dst[3] = v.w;
    }
    __syncthreads();
    int wid = t >> 6, lane = t & 63;
    int row = r0 + lane;
    int c0 = __builtin_amdgcn_readfirstlane(wid * 32);
    float acc[32];
    #pragma unroll
    for (int c = 0; c < 32; c++) acc[c] = 0.f;
    const float* xr = &xt[lane * 129];
    const float* wp = W1 + c0;
    #pragma unroll 2
    for (int k = 0; k < 128; k++) {
        float xv = xr[k];
        const float* wk = wp + k * 128;
        #pragma unroll
        for (int c = 0; c < 32; c++) acc[c] += xv * wk[c];
    }
    if (row < NN) {
        unsigned* orow = xs1b + (size_t)row * 64 + wid * 16;
        #pragma unroll
        for (int j = 0; j < 4; j++) {
            uint4 pk;
            pk.x = pack2bf(acc[8*j+0], acc[8*j+1]);
            pk.y = pack2bf(acc[8*j+2], acc[8*j+3]);
            pk.z = pack2bf(acc[8*j+4], acc[8*j+5]);
            pk.w = pack2bf(acc[8*j+6], acc[8*j+7]);
            *(uint4*)(orow + 4*j) = pk;
        }
        float ps = 0.f, pd = 0.f;
        #pragma unroll
        for (int c = 0; c < 32; c++) { ps += acc[c] * asv[c0 + c]; pd += acc[c] * adv[c0 + c]; }
        as1[row * 4 + wid] = ps;
        ad1[row * 4 + wid] = pd;
    }
}

// ---------------- Layer 1 aggregation: phase-split + MLP-batched gathers ----------------

__global__ void k_agg1(const unsigned* __restrict__ xs1b, const float* __restrict__ as1,
                       const float* __restrict__ ad1, const int* __restrict__ rowptr,
                       const int2* __restrict__ edge2,
                       const float* __restrict__ params, const float* __restrict__ b1,
                       float* __restrict__ h1) {
    int wid = threadIdx.x >> 6, lane = threadIdx.x & 63;
    int n = blockIdx.x * 4 + wid;
    if (n >= NN) return;
    int h4 = lane & 3;          // head owned in phase 1
    int h  = lane >> 4;         // head mapped to channels in phase 2
    float ceP  = params[2 + h4];
    float adnP = ad1[n * 4 + h4];
    float meanw = params[1];
    float aself = as1[n * 4 + h] + ad1[n * 4 + h] + meanw * params[2 + h];
    aself = aself > 0.f ? aself : NEG * aself;
    float qs = __expf(aself);
    unsigned us = xs1b[(size_t)n * 64 + lane];
    float s  = qs;
    float ax = qs * __uint_as_float(us << 16);
    float ay = qs * __uint_as_float(us & 0xFFFF0000u);
    int lo = rowptr[n], hi = rowptr[n + 1];
    for (int base = lo; base < hi; base += 16) {
        // phase 1: lane (e,h4) computes q for edge base+e, head h4
        int e = lane >> 2;
        int idx = base + e;
        int cx = 0;
        float q = 0.f;
        if (idx < hi) {
            int2 cv = edge2[idx];
            cx = cv.x;
            float a = as1[cx * 4 + h4] + adnP + __int_as_float(cv.y) * ceP;
            a = a > 0.f ? a : NEG * a;
            q = __expf(a);
        }
        int m = hi - base; if (m > 16) m = 16;
        // phase 2: batched broadcast+gather (8 loads in flight), then accumulate
        int j = 0;
        for (; j + 8 <= m; j += 8) {
            int cj[8]; float qj[8]; unsigned vv[8];
            #pragma unroll
            for (int u = 0; u < 8; u++) {
                cj[u] = __shfl(cx, 4 * (j + u), 64);
                qj[u] = __shfl(q, 4 * (j + u) + h, 64);
            }
            #pragma unroll
            for (int u = 0; u < 8; u++) vv[u] = xs1b[(size_t)cj[u] * 64 + lane];
            #pragma unroll
            for (int u = 0; u < 8; u++) {
                s += qj[u];
                ax += qj[u] * __uint_as_float(vv[u] << 16);
                ay += qj[u] * __uint_as_float(vv[u] & 0xFFFF0000u);
            }
        }
        for (; j < m; j++) {
            int cj = __shfl(cx, 4 * j, 64);
            float qj = __shfl(q, 4 * j + h, 64);
            unsigned u = xs1b[(size_t)cj * 64 + lane];
            s += qj;
            ax += qj * __uint_as_float(u << 16);
            ay += qj * __uint_as_float(u & 0xFFFF0000u);
        }
    }
    float inv = 1.0f / (s + 1e-16f);
    float o0 = ax * inv + b1[2 * lane];
    float o1 = ay * inv + b1[2 * lane + 1];
    o0 = o0 > 0.f ? o0 : (__expf(o0) - 1.0f);   // ELU
    o1 = o1 > 0.f ? o1 : (__expf(o1) - 1.0f);
    *(float2*)(h1 + (size_t)n * 128 + 2 * lane) = make_float2(o0, o1);
}

// ---------------- Layer 2 GEMM: lane=row, wave=16-col chunk, h1 staged in LDS; xs2 out bf16 ----------------

__global__ void __launch_bounds__(256, 4)
k_gemm2(const float* __restrict__ h1, const float* __restrict__ W2,
        const float* __restrict__ asv, const float* __restrict__ adv,
        unsigned* __restrict__ xs2b, float* __restrict__ as2, float* __restrict__ ad2) {
    __shared__ float xt[64 * 129];
    __shared__ float pp[2][4][64];
    int t = threadIdx.x;
    int r0 = blockIdx.x * 64;
    for (int i = t; i < 2048; i += 256) {
        int row = i >> 5;
        int c4 = i & 31;
        float4 v = (r0 + row < NN) ? ((const float4*)h1)[(size_t)(r0 + row) * 32 + c4]
                                   : make_float4(0.f, 0.f, 0.f, 0.f);
        float* dst = &xt[row * 129 + c4 * 4];
        dst[0] = v.x; dst[1] = v.y; dst[2] = v.z; dst[3] = v.w;
    }
    __syncthreads();
    int wid = t >> 6, lane = t & 63;
    int row = r0 + lane;
    int c0 = __builtin_amdgcn_readfirstlane(wid * 16);
    float acc[16];
    #pragma unroll
    for (int c = 0; c < 16; c++) acc[c] = 0.f;
    const float* xr = &xt[lane * 129];
    const float* wp = W2 + c0;
    #pragma unroll 2
    for (int k = 0; k < 128; k++) {
        float xv = xr[k];
        const float* wk = wp + k * 64;
        #pragma unroll
        for (int c = 0; c < 16; c++) acc[c] += xv * wk[c];
    }
    float ps = 0.f, pd = 0.f;
    #pragma unroll
    for (int c = 0; c < 16; c++) { ps += acc[c] * asv[c0 + c]; pd += acc[c] * adv[c0 + c]; }
    pp[0][wid][lane] = ps;
    pp[1][wid][lane] = pd;
    if (row < NN) {
        unsigned* orow = xs2b + (size_t)row * 32 + wid * 8;
        #pragma unroll
        for (int j = 0; j < 2; j++) {
            uint4 pk;
            pk.x = pack2bf(acc[8*j+0], acc[8*j+1]);
            pk.y = pack2bf(acc[8*j+2], acc[8*j+3]);
            pk.z = pack2bf(acc[8*j+4], acc[8*j+5]);
            pk.w = pack2bf(acc[8*j+6], acc[8*j+7]);
            *(uint4*)(orow + 4*j) = pk;
        }
    }
    __syncthreads();
    if (wid == 0 && row < NN) {
        as2[row] = pp[0][0][lane] + pp[0][1][lane] + pp[0][2][lane] + pp[0][3][lane];
        ad2[row] = pp[1][0][lane] + pp[1][1][lane] + pp[1][2][lane] + pp[1][3][lane];
    }
}

// ---------------- Layer 2 aggregation: phase-split + MLP-batched gathers ----------------

__global__ void k_agg2(const unsigned short* __restrict__ xs2h, const float* __restrict__ as2,
                       const float* __restrict__ ad2, const int* __restrict__ rowptr,
                       const int2* __restrict__ edge2,
                       const float* __restrict__ params, const float* __restrict__ b2,
                       float* __restrict__ out) {
    int wid = threadIdx.x >> 6, lane = threadIdx.x & 63;
    int n = blockIdx.x * 4 + wid;
    if (n >= NN) return;
    float ce = params[6];
    float meanw = params[1];
    float adn = ad2[n];
    float aself = as2[n] + adn + meanw * ce;
    aself = aself > 0.f ? aself : NEG * aself;
    float qs = __expf(aself);
    float s = qs;
    float ac = qs * __uint_as_float(((unsigned)xs2h[(size_t)n * 64 + lane]) << 16);
    int lo = rowptr[n], hi = rowptr[n + 1];
    for (int base = lo; base < hi; base += 64) {
        int idx = base + lane;
        int cx = 0;
        float q = 0.f;
        if (idx < hi) {
            int2 cv = edge2[idx];
            cx = cv.x;
            float a = as2[cx] + adn + __int_as_float(cv.y) * ce;
            a = a > 0.f ? a : NEG * a;
            q = __expf(a);
        }
        int m = hi - base; if (m > 64) m = 64;
        int j = 0;
        for (; j + 8 <= m; j += 8) {
            int cj[8]; float qj[8]; unsigned short vv[8];
            #pragma unroll
            for (int u = 0; u < 8; u++) {
                cj[u] = __shfl(cx, j + u, 64);
                qj[u] = __shfl(q, j + u, 64);
            }
            #pragma unroll
            for (int u = 0; u < 8; u++) vv[u] = xs2h[(size_t)cj[u] * 64 + lane];
            #pragma unroll
            for (int u = 0; u < 8; u++) {
                s += qj[u];
                ac += qj[u] * __uint_as_float(((unsigned)vv[u]) << 16);
            }
        }
        for (; j < m; j++) {
            int cj = __shfl(cx, j, 64);
            float qj = __shfl(q, j, 64);
            float v = __uint_as_float(((unsigned)xs2h[(size_t)cj * 64 + lane]) << 16);
            s += qj;
            ac += qj * v;
        }
    }
    out[(size_t)n * 64 + lane] = ac / (s + 1e-16f) + b2[lane];
}

extern "C" void kernel_launch(void* const* d_in, const int* in_sizes, int n_in,
                              void* d_out, int out_size, void* d_ws, size_t ws_size,
                              hipStream_t stream) {
    const float* x    = (const float*)d_in[0];
    const int*   ei   = (const int*)d_in[1];
    const float* ew   = (const float*)d_in[2];
    const float* W1   = (const float*)d_in[3];
    const float* as1v = (const float*)d_in[4];
    const float* ad1v = (const float*)d_in[5];
    const float* ae1v = (const float*)d_in[6];
    const float* We1  = (const float*)d_in[7];
    const float* b1   = (const float*)d_in[8];
    const float* W2   = (const float*)d_in[9];
    const float* as2v = (const float*)d_in[10];
    const float* ad2v = (const float*)d_in[11];
    const float* ae2v = (const float*)d_in[12];
    const float* We2  = (const float*)d_in[13];
    const float* b2   = (const float*)d_in[14];
    const int* srcI = ei;
    const int* dstI = ei + NE;

    float* wsf = (float*)d_ws;
    size_t off = 0;
    auto alloc = [&](size_t nelts) { float* p = wsf + off; off += (nelts + 63) & ~(size_t)63; return p; };
    float*    params = alloc(64);
    int*      deg    = (int*)alloc(NN);            // padded to 100032
    int*      bcur   = (int*)alloc(64);
    int*      rowptr = (int*)alloc(NN + 1);
    int*      cursor = (int*)alloc(NN);
    int*      bsum   = (int*)alloc(NBLK);
    int*      bpre   = (int*)alloc(NBLK);
    size_t    binsOff = off;
    int*      bdst   = (int*)alloc((size_t)NBUCK * CAPB);        // 2.4M ints
    int2*     bse    = (int2*)alloc((size_t)NBUCK * CAPB * 2);   // 4.8M ints
    int2*     edge2  = (int2*)alloc((size_t)NE * 2);
    float*    as1    = alloc(NN * 4);
    float*    ad1    = alloc(NN * 4);
    float*    h1     = alloc((size_t)NN * 128);
    // xs1b overlays the bin region (bdst+bse = 7.2M words >= 6.4M; bins dead before gemm1)
    unsigned* xs1b   = (unsigned*)(wsf + binsOff);
    unsigned* xs2b   = xs1b;
    float*    as2 = as1;
    float*    ad2 = ad1;

    // zero params + deg + bcur (contiguous at ws start)
    hipMemsetAsync(d_ws, 0, (64 + 100032 + 64) * sizeof(float), stream);

    k_binA <<<NBINBLK, 256, 0, stream>>>(srcI, dstI, ew, bcur, bdst, bse, params);
    k_histB<<<2048, 256, 0, stream>>>(bdst, bcur, deg);
    k_scanA<<<NBLK, 256, 0, stream>>>(deg, bsum);
    k_scanB<<<1, 128, 0, stream>>>(bsum, bpre, rowptr);
    k_scanC<<<NBLK, 256, 0, stream>>>(deg, bpre, rowptr, cursor);
    k_binB <<<2048, 256, 0, stream>>>(bdst, bse, bcur, cursor, edge2);
    k_setup<<<1, 128, 0, stream>>>(We1, ae1v, We2, ae2v, params);
    k_gemm1<<<(NN + 63) / 64, 256, 0, stream>>>(x, W1, as1v, ad1v, xs1b, as1, ad1);
    k_agg1 <<<25000, 256, 0, stream>>>(xs1b, as1, ad1, rowptr, edge2, params, b1, h1);
    k_gemm2<<<(NN + 63) / 64, 256, 0, stream>>>(h1, W2, as2v, ad2v, xs2b, as2, ad2);
    k_agg2 <<<25000, 256, 0, stream>>>((const unsigned short*)xs2b, as2, ad2, rowptr, edge2, params, b2, (float*)d_out);
}

// Round 10
// 428.345 us; speedup vs baseline: 3.0014x; 1.0509x over previous
//
#include <hip/hip_runtime.h>
#include <math.h>

#define NN 100000
#define NE 1600000
#define DIN 128
#define NH 4
#define C1 32
#define C2 64
#define NEG 0.2f

#define SCAN_CHUNK 1024
#define NBLK ((NN + SCAN_CHUNK - 1) / SCAN_CHUNK)   // 98

#define NBUCK 8
#define BUCKN (NN / NBUCK)          // 12500 nodes per bucket
#define CAPB 300000                 // fixed bucket capacity (uniform dst -> ~200K each)
#define BIN_CHUNK 4096
#define NBINBLK ((NE + BIN_CHUNK - 1) / BIN_CHUNK)  // 391

__device__ __forceinline__ unsigned bf16rtn(float f) {
    unsigned b = __float_as_uint(f);
    return (b + 0x7FFFu + ((b >> 16) & 1u)) >> 16;
}
__device__ __forceinline__ unsigned pack2bf(float lo, float hi) {
    return bf16rtn(lo) | (bf16rtn(hi) << 16);
}

__global__ void k_setup(const float* __restrict__ We1, const float* __restrict__ ae1,
                        const float* __restrict__ We2, const float* __restrict__ ae2,
                        float* __restrict__ params) {
    __shared__ float sm[128];
    int t = threadIdx.x;
    sm[t] = We1[t] * ae1[t];
    __syncthreads();
    if (t < 4) {
        float s = 0.f;
        for (int c = 0; c < 32; c++) s += sm[t * 32 + c];
        params[2 + t] = s;            // ce1[h]
    }
    __syncthreads();
    if (t < 64) sm[t] = We2[t] * ae2[t];
    __syncthreads();
    if (t == 0) {
        float s = 0.f;
        for (int c = 0; c < 64; c++) s += sm[c];
        params[6] = s;                // ce2
        params[1] = params[0] / (float)NE;  // mean edge weight
    }
}

// ---- pass 1: bin edges into 8 dst-range buckets (fixed-capacity regions) ----
__global__ void k_binA(const int* __restrict__ srcI, const int* __restrict__ dstI,
                       const float* __restrict__ ew, int* __restrict__ bcur,
                       int* __restrict__ bdst, int2* __restrict__ bse,
                       float* __restrict__ params) {
    __shared__ int hcnt[NBUCK], hbase[NBUCK], hoff[NBUCK];
    int t = threadIdx.x;
    int e0 = blockIdx.x * BIN_CHUNK;
    if (t < NBUCK) hcnt[t] = 0;
    __syncthreads();
    for (int i = t; i < BIN_CHUNK; i += 256) {
        int e = e0 + i;
        if (e < NE) atomicAdd(&hcnt[dstI[e] / BUCKN], 1);
    }
    __syncthreads();
    if (t < NBUCK) { hbase[t] = atomicAdd(&bcur[t], hcnt[t]); hoff[t] = 0; }
    __syncthreads();
    float locw = 0.f;
    for (int i = t; i < BIN_CHUNK; i += 256) {
        int e = e0 + i;
        if (e < NE) {
            int d = dstI[e];
            float w = ew[e];
            locw += w;
            int b = d / BUCKN;
            int p = b * CAPB + hbase[b] + atomicAdd(&hoff[b], 1);
            bdst[p] = d;
            bse[p] = make_int2(srcI[e], __float_as_int(w));
        }
    }
    for (int o = 32; o > 0; o >>= 1) locw += __shfl_down(locw, o, 64);
    if ((t & 63) == 0) atomicAdd(&params[0], locw);
}

// ---- per-node degree histogram, XCD-local per bucket ----
__global__ void k_histB(const int* __restrict__ bdst, const int* __restrict__ bcur,
                        int* __restrict__ deg) {
    int b = blockIdx.x & (NBUCK - 1);
    int slice = blockIdx.x >> 3;
    int cnt = bcur[b];
    int lo = b * CAPB;
    int per = (cnt + 255) / 256;
    int s0 = lo + slice * per;
    int s1 = min(s0 + per, lo + cnt);
    for (int i = s0 + threadIdx.x; i < s1; i += 256)
        atomicAdd(&deg[bdst[i]], 1);
}

// block partial sums
__global__ void k_scanA(const int* __restrict__ deg, int* __restrict__ bsum) {
    __shared__ int ws[4];
    int b = blockIdx.x;
    int base = b * SCAN_CHUNK;
    int t = threadIdx.x;
    int s = 0;
    for (int i = t; i < SCAN_CHUNK; i += 256) {
        int idx = base + i;
        if (idx < NN) s += deg[idx];
    }
    for (int o = 32; o > 0; o >>= 1) s += __shfl_down(s, o, 64);
    int lane = t & 63, wid = t >> 6;
    if (lane == 0) ws[wid] = s;
    __syncthreads();
    if (t == 0) bsum[b] = ws[0] + ws[1] + ws[2] + ws[3];
}

__global__ void k_scanB(const int* __restrict__ bsum, int* __restrict__ bpre,
                        int* __restrict__ rowptr) {
    __shared__ int wtot[2];
    int t = threadIdx.x;
    int lane = t & 63, wid = t >> 6;
    int v = (t < NBLK) ? bsum[t] : 0;
    int inc = v;
    for (int o = 1; o < 64; o <<= 1) { int u = __shfl_up(inc, o, 64); if (lane >= o) inc += u; }
    if (lane == 63) wtot[wid] = inc;
    __syncthreads();
    if (wid == 1) inc += wtot[0];
    if (t < NBLK) bpre[t] = inc - v;          // exclusive prefix
    if (t == NBLK - 1) rowptr[NN] = inc;      // total == NE
}

__global__ void k_scanC(const int* __restrict__ deg, const int* __restrict__ bpre,
                        int* __restrict__ rowptr, int* __restrict__ cursor) {
    __shared__ int wtot[4];
    int b = blockIdx.x;
    int t = threadIdx.x;
    int lane = t & 63, wid = t >> 6;
    int idx0 = b * SCAN_CHUNK + t * 4;
    int d[4];
    int s = 0;
    #pragma unroll
    for (int j = 0; j < 4; j++) {
        int idx = idx0 + j;
        d[j] = (idx < NN) ? deg[idx] : 0;
        s += d[j];
    }
    int inc = s;
    for (int o = 1; o < 64; o <<= 1) { int u = __shfl_up(inc, o, 64); if (lane >= o) inc += u; }
    if (lane == 63) wtot[wid] = inc;
    __syncthreads();
    int add = bpre[b];
    for (int w = 0; w < wid; w++) add += wtot[w];
    int excl = inc - s + add;
    #pragma unroll
    for (int j = 0; j < 4; j++) {
        int idx = idx0 + j;
        if (idx < NN) { rowptr[idx] = excl; cursor[idx] = excl; }
        excl += d[j];
    }
}

// ---- pass 2: scatter within bucket; bucket = blockIdx.x & 7 tracks round-robin block->XCD ----
__global__ void k_binB(const int* __restrict__ bdst, const int2* __restrict__ bse,
                       const int* __restrict__ bcur, int* __restrict__ cursor,
                       int2* __restrict__ edge2) {
    int b = blockIdx.x & (NBUCK - 1);
    int slice = blockIdx.x >> 3;
    int cnt = bcur[b];
    int lo = b * CAPB;
    int per = (cnt + 255) / 256;
    int s0 = lo + slice * per;
    int s1 = min(s0 + per, lo + cnt);
    for (int i = s0 + threadIdx.x; i < s1; i += 256) {
        int d = bdst[i];
        int idx = atomicAdd(&cursor[d], 1);
        edge2[idx] = bse[i];
    }
}

// ---------------- Layer 1 GEMM: lane=row, wave=head(32 cols); x staged bf16 in LDS (16.6 KB) ----------------

__global__ void __launch_bounds__(256, 8)
k_gemm1(const float* __restrict__ x, const float* __restrict__ W1,
        const float* __restrict__ asv, const float* __restrict__ adv,
        unsigned* __restrict__ xs1b, float* __restrict__ as1, float* __restrict__ ad1) {
    __shared__ unsigned xt[64 * 65];   // [row][k2], 2 bf16 per dword, stride 65 (reads 2-way free)
    int t = threadIdx.x;
    int r0 = blockIdx.x * 64;
    for (int i = t; i < 2048; i += 256) {
        int row = i >> 5;
        int c4 = i & 31;
        float4 v = (r0 + row < NN) ? ((const float4*)x)[(size_t)(r0 + row) * 32 + c4]
                                   : make_float4(0.f, 0.f, 0.f, 0.f);
        xt[row * 65 + c4 * 2]     = pack2bf(v.x, v.y);
        xt[row * 65 + c4 * 2 + 1] = pack2bf(v.z, v.w);
    }
    __syncthreads();
    int wid = t >> 6, lane = t & 63;
    int row = r0 + lane;
    int c0 = __builtin_amdgcn_readfirstlane(wid * 32);
    float acc[32];
    #pragma unroll
    for (int c = 0; c < 32; c++) acc[c] = 0.f;
    const unsigned* xr = &xt[lane * 65];
    const float* wp = W1 + c0;
    #pragma unroll 2
    for (int k2 = 0; k2 < 64; k2++) {
        unsigned v = xr[k2];
        float x0 = __uint_as_float(v << 16);
        float x1 = __uint_as_float(v & 0xFFFF0000u);
        const float* w0 = wp + (2 * k2) * 128;
        const float* w1 = w0 + 128;
        #pragma unroll
        for (int c = 0; c < 32; c++) acc[c] += x0 * w0[c] + x1 * w1[c];
    }
    if (row < NN) {
        unsigned* orow = xs1b + (size_t)row * 64 + wid * 16;
        #pragma unroll
        for (int j = 0; j < 4; j++) {
            uint4 pk;
            pk.x = pack2bf(acc[8*j+0], acc[8*j+1]);
            pk.y = pack2bf(acc[8*j+2], acc[8*j+3]);
            pk.z = pack2bf(acc[8*j+4], acc[8*j+5]);
            pk.w = pack2bf(acc[8*j+6], acc[8*j+7]);
            *(uint4*)(orow + 4*j) = pk;
        }
        float ps = 0.f, pd = 0.f;
        #pragma unroll
        for (int c = 0; c < 32; c++) { ps += acc[c] * asv[c0 + c]; pd += acc[c] * adv[c0 + c]; }
        as1[row * 4 + wid] = ps;
        ad1[row * 4 + wid] = pd;
    }
}

// ---------------- Layer 1 aggregation: phase-split + MLP-batched gathers; h1 out bf16-packed ----------------

__global__ void k_agg1(const unsigned* __restrict__ xs1b, const float* __restrict__ as1,
                       const float* __restrict__ ad1, const int* __restrict__ rowptr,
                       const int2* __restrict__ edge2,
                       const float* __restrict__ params, const float* __restrict__ b1,
                       unsigned* __restrict__ h1b) {
    int wid = threadIdx.x >> 6, lane = threadIdx.x & 63;
    int n = blockIdx.x * 4 + wid;
    if (n >= NN) return;
    int h4 = lane & 3;          // head owned in phase 1
    int h  = lane >> 4;         // head mapped to channels in phase 2
    float ceP  = params[2 + h4];
    float adnP = ad1[n * 4 + h4];
    float meanw = params[1];
    float aself = as1[n * 4 + h] + ad1[n * 4 + h] + meanw * params[2 + h];
    aself = aself > 0.f ? aself : NEG * aself;
    float qs = __expf(aself);
    unsigned us = xs1b[(size_t)n * 64 + lane];
    float s  = qs;
    float ax = qs * __uint_as_float(us << 16);
    float ay = qs * __uint_as_float(us & 0xFFFF0000u);
    int lo = rowptr[n], hi = rowptr[n + 1];
    for (int base = lo; base < hi; base += 16) {
        int e = lane >> 2;
        int idx = base + e;
        int cx = 0;
        float q = 0.f;
        if (idx < hi) {
            int2 cv = edge2[idx];
            cx = cv.x;
            float a = as1[cx * 4 + h4] + adnP + __int_as_float(cv.y) * ceP;
            a = a > 0.f ? a : NEG * a;
            q = __expf(a);
        }
        int m = hi - base; if (m > 16) m = 16;
        int j = 0;
        for (; j + 8 <= m; j += 8) {
            int cj[8]; float qj[8]; unsigned vv[8];
            #pragma unroll
            for (int u = 0; u < 8; u++) {
                cj[u] = __shfl(cx, 4 * (j + u), 64);
                qj[u] = __shfl(q, 4 * (j + u) + h, 64);
            }
            #pragma unroll
            for (int u = 0; u < 8; u++) vv[u] = xs1b[(size_t)cj[u] * 64 + lane];
            #pragma unroll
            for (int u = 0; u < 8; u++) {
                s += qj[u];
                ax += qj[u] * __uint_as_float(vv[u] << 16);
                ay += qj[u] * __uint_as_float(vv[u] & 0xFFFF0000u);
            }
        }
        for (; j < m; j++) {
            int cj = __shfl(cx, 4 * j, 64);
            float qj = __shfl(q, 4 * j + h, 64);
            unsigned u = xs1b[(size_t)cj * 64 + lane];
            s += qj;
            ax += qj * __uint_as_float(u << 16);
            ay += qj * __uint_as_float(u & 0xFFFF0000u);
        }
    }
    float inv = 1.0f / (s + 1e-16f);
    float o0 = ax * inv + b1[2 * lane];
    float o1 = ay * inv + b1[2 * lane + 1];
    o0 = o0 > 0.f ? o0 : (__expf(o0) - 1.0f);   // ELU
    o1 = o1 > 0.f ? o1 : (__expf(o1) - 1.0f);
    h1b[(size_t)n * 64 + lane] = pack2bf(o0, o1);
}

// ---------------- Layer 2 GEMM: lane=row, wave=16 cols; h1 (bf16-packed) staged in LDS ----------------

__global__ void __launch_bounds__(256, 8)
k_gemm2(const unsigned* __restrict__ h1b, const float* __restrict__ W2,
        const float* __restrict__ asv, const float* __restrict__ adv,
        unsigned* __restrict__ xs2b, float* __restrict__ as2, float* __restrict__ ad2) {
    __shared__ unsigned xt[64 * 65];     // 16.6 KB
    __shared__ float pp[2][4][64];       // cross-wave alpha partials (2 KB)
    int t = threadIdx.x;
    int r0 = blockIdx.x * 64;
    for (int i = t; i < 1024; i += 256) {
        int row = i >> 4;
        int q = i & 15;
        uint4 v = (r0 + row < NN) ? ((const uint4*)h1b)[(size_t)(r0 + row) * 16 + q]
                                  : make_uint4(0u, 0u, 0u, 0u);
        unsigned* dst = &xt[row * 65 + q * 4];
        dst[0] = v.x; dst[1] = v.y; dst[2] = v.z; dst[3] = v.w;
    }
    __syncthreads();
    int wid = t >> 6, lane = t & 63;
    int row = r0 + lane;
    int c0 = __builtin_amdgcn_readfirstlane(wid * 16);
    float acc[16];
    #pragma unroll
    for (int c = 0; c < 16; c++) acc[c] = 0.f;
    const unsigned* xr = &xt[lane * 65];
    const float* wp = W2 + c0;
    #pragma unroll 2
    for (int k2 = 0; k2 < 64; k2++) {
        unsigned v = xr[k2];
        float x0 = __uint_as_float(v << 16);
        float x1 = __uint_as_float(v & 0xFFFF0000u);
        const float* w0 = wp + (2 * k2) * 64;
        const float* w1 = w0 + 64;
        #pragma unroll
        for (int c = 0; c < 16; c++) acc[c] += x0 * w0[c] + x1 * w1[c];
    }
    float ps = 0.f, pd = 0.f;
    #pragma unroll
    for (int c = 0; c < 16; c++) { ps += acc[c] * asv[c0 + c]; pd += acc[c] * adv[c0 + c]; }
    pp[0][wid][lane] = ps;
    pp[1][wid][lane] = pd;
    if (row < NN) {
        unsigned* orow = xs2b + (size_t)row * 32 + wid * 8;
        #pragma unroll
        for (int j = 0; j < 2; j++) {
            uint4 pk;
            pk.x = pack2bf(acc[8*j+0], acc[8*j+1]);
            pk.y = pack2bf(acc[8*j+2], acc[8*j+3]);
            pk.z = pack2bf(acc[8*j+4], acc[8*j+5]);
            pk.w = pack2bf(acc[8*j+6], acc[8*j+7]);
            *(uint4*)(orow + 4*j) = pk;
        }
    }
    __syncthreads();
    if (wid == 0 && row < NN) {
        as2[row] = pp[0][0][lane] + pp[0][1][lane] + pp[0][2][lane] + pp[0][3][lane];
        ad2[row] = pp[1][0][lane] + pp[1][1][lane] + pp[1][2][lane] + pp[1][3][lane];
    }
}

// ---------------- Layer 2 aggregation: phase-split + MLP-batched gathers ----------------

__global__ void k_agg2(const unsigned short* __restrict__ xs2h, const float* __restrict__ as2,
                       const float* __restrict__ ad2, const int* __restrict__ rowptr,
                       const int2* __restrict__ edge2,
                       const float* __restrict__ params, const float* __restrict__ b2,
                       float* __restrict__ out) {
    int wid = threadIdx.x >> 6, lane = threadIdx.x & 63;
    int n = blockIdx.x * 4 + wid;
    if (n >= NN) return;
    float ce = params[6];
    float meanw = params[1];
    float adn = ad2[n];
    float aself = as2[n] + adn + meanw * ce;
    aself = aself > 0.f ? aself : NEG * aself;
    float qs = __expf(aself);
    float s = qs;
    float ac = qs * __uint_as_float(((unsigned)xs2h[(size_t)n * 64 + lane]) << 16);
    int lo = rowptr[n], hi = rowptr[n + 1];
    for (int base = lo; base < hi; base += 64) {
        int idx = base + lane;
        int cx = 0;
        float q = 0.f;
        if (idx < hi) {
            int2 cv = edge2[idx];
            cx = cv.x;
            float a = as2[cx] + adn + __int_as_float(cv.y) * ce;
            a = a > 0.f ? a : NEG * a;
            q = __expf(a);
        }
        int m = hi - base; if (m > 64) m = 64;
        int j = 0;
        for (; j + 8 <= m; j += 8) {
            int cj[8]; float qj[8]; unsigned short vv[8];
            #pragma unroll
            for (int u = 0; u < 8; u++) {
                cj[u] = __shfl(cx, j + u, 64);
                qj[u] = __shfl(q, j + u, 64);
            }
            #pragma unroll
            for (int u = 0; u < 8; u++) vv[u] = xs2h[(size_t)cj[u] * 64 + lane];
            #pragma unroll
            for (int u = 0; u < 8; u++) {
                s += qj[u];
                ac += qj[u] * __uint_as_float(((unsigned)vv[u]) << 16);
            }
        }
        for (; j < m; j++) {
            int cj = __shfl(cx, j, 64);
            float qj = __shfl(q, j, 64);
            float v = __uint_as_float(((unsigned)xs2h[(size_t)cj * 64 + lane]) << 16);
            s += qj;
            ac += qj * v;
        }
    }
    out[(size_t)n * 64 + lane] = ac / (s + 1e-16f) + b2[lane];
}

extern "C" void kernel_launch(void* const* d_in, const int* in_sizes, int n_in,
                              void* d_out, int out_size, void* d_ws, size_t ws_size,
                              hipStream_t stream) {
    const float* x    = (const float*)d_in[0];
    const int*   ei   = (const int*)d_in[1];
    const float* ew   = (const float*)d_in[2];
    const float* W1   = (const float*)d_in[3];
    const float* as1v = (const float*)d_in[4];
    const float* ad1v = (const float*)d_in[5];
    const float* ae1v = (const float*)d_in[6];
    const float* We1  = (const float*)d_in[7];
    const float* b1   = (const float*)d_in[8];
    const float* W2   = (const float*)d_in[9];
    const float* as2v = (const float*)d_in[10];
    const float* ad2v = (const float*)d_in[11];
    const float* ae2v = (const float*)d_in[12];
    const float* We2  = (const float*)d_in[13];
    const float* b2   = (const float*)d_in[14];
    const int* srcI = ei;
    const int* dstI = ei + NE;

    float* wsf = (float*)d_ws;
    size_t off = 0;
    auto alloc = [&](size_t nelts) { float* p = wsf + off; off += (nelts + 63) & ~(size_t)63; return p; };
    float*    params = alloc(64);
    int*      deg    = (int*)alloc(NN);            // padded to 100032
    int*      bcur   = (int*)alloc(64);
    int*      rowptr = (int*)alloc(NN + 1);
    int*      cursor = (int*)alloc(NN);
    int*      bsum   = (int*)alloc(NBLK);
    int*      bpre   = (int*)alloc(NBLK);
    size_t    binsOff = off;
    int*      bdst   = (int*)alloc((size_t)NBUCK * CAPB);        // 2.4M ints
    int2*     bse    = (int2*)alloc((size_t)NBUCK * CAPB * 2);   // 4.8M ints
    int2*     edge2  = (int2*)alloc((size_t)NE * 2);
    float*    as1    = alloc(NN * 4);
    float*    ad1    = alloc(NN * 4);
    unsigned* h1b    = (unsigned*)alloc((size_t)NN * 64);        // bf16-packed h1 [N][128]
    // xs1b overlays the bin region (bdst+bse = 7.2M words >= 6.4M; bins dead before gemm1)
    unsigned* xs1b   = (unsigned*)(wsf + binsOff);
    unsigned* xs2b   = xs1b;
    float*    as2 = as1;
    float*    ad2 = ad1;

    // zero params + deg + bcur (contiguous at ws start)
    hipMemsetAsync(d_ws, 0, (64 + 100032 + 64) * sizeof(float), stream);

    k_binA <<<NBINBLK, 256, 0, stream>>>(srcI, dstI, ew, bcur, bdst, bse, params);
    k_histB<<<2048, 256, 0, stream>>>(bdst, bcur, deg);
    k_scanA<<<NBLK, 256, 0, stream>>>(deg, bsum);
    k_scanB<<<1, 128, 0, stream>>>(bsum, bpre, rowptr);
    k_scanC<<<NBLK, 256, 0, stream>>>(deg, bpre, rowptr, cursor);
    k_binB <<<2048, 256, 0, stream>>>(bdst, bse, bcur, cursor, edge2);
    k_setup<<<1, 128, 0, stream>>>(We1, ae1v, We2, ae2v, params);
    k_gemm1<<<(NN + 63) / 64, 256, 0, stream>>>(x, W1, as1v, ad1v, xs1b, as1, ad1);
    k_agg1 <<<25000, 256, 0, stream>>>(xs1b, as1, ad1, rowptr, edge2, params, b1, h1b);
    k_gemm2<<<(NN + 63) / 64, 256, 0, stream>>>(h1b, W2, as2v, ad2v, xs2b, as2, ad2);
    k_agg2 <<<25000, 256, 0, stream>>>((const unsigned short*)xs2b, as2, ad2, rowptr, edge2, params, b2, (float*)d_out);
}